// Round 6
// baseline (157.727 us; speedup 1.0000x reference)
//
#include <hip/hip_runtime.h>
#include <math.h>

#define S_ 1024
#define T_ 32
#define SCALE_F 0.7071067811865476f

typedef unsigned int uint;
typedef unsigned short ushort;
typedef __bf16 bf16x8 __attribute__((ext_vector_type(8)));
typedef float f32x16 __attribute__((ext_vector_type(16)));

union FragU { uint4 q; bf16x8 v; };

#define MFMA(a, b, c) __builtin_amdgcn_mfma_f32_32x32x16_bf16((a), (b), (c), 0, 0, 0)

__device__ __forceinline__ uint rne16(float f) {
  uint u = __builtin_bit_cast(uint, f);
  u += 0x7fffu + ((u >> 16) & 1u);
  return u >> 16;
}

__device__ __forceinline__ void split8a(const float* f, uint4& hi, uint4& lo) {
  uint h[8], m[8];
#pragma unroll
  for (int i = 0; i < 8; ++i) {
    uint u = __builtin_bit_cast(uint, f[i]);
    h[i] = u >> 16;
    float fh = __builtin_bit_cast(float, u & 0xffff0000u);
    m[i] = __builtin_bit_cast(uint, f[i] - fh) >> 16;
  }
  hi = make_uint4(h[0] | (h[1] << 16), h[2] | (h[3] << 16),
                  h[4] | (h[5] << 16), h[6] | (h[7] << 16));
  lo = make_uint4(m[0] | (m[1] << 16), m[2] | (m[3] << 16),
                  m[4] | (m[5] << 16), m[6] | (m[7] << 16));
}

__device__ __forceinline__ uint4 rne8(const float4& A, const float4& B) {
  float f[8] = {A.x, A.y, A.z, A.w, B.x, B.y, B.z, B.w};
  uint h[8];
#pragma unroll
  for (int i = 0; i < 8; ++i) h[i] = rne16(f[i]);
  return make_uint4(h[0] | (h[1] << 16), h[2] | (h[3] << 16),
                    h[4] | (h[5] << 16), h[6] | (h[7] << 16));
}

// ---------------------------------------------------------------------------
// Bulk f32->bf16: X (2M el), Wq, Wk, Wv, Wo (1M each). 8 el/thread.
// ---------------------------------------------------------------------------
__global__ __launch_bounds__(256) void k_cvtall(
    const float* __restrict__ X, const float* __restrict__ Wq,
    const float* __restrict__ Wk, const float* __restrict__ Wv,
    const float* __restrict__ Wo, ushort* __restrict__ Xb,
    ushort* __restrict__ Wqb, ushort* __restrict__ Wkb,
    ushort* __restrict__ Wvb, ushort* __restrict__ Wob) {
  int i = blockIdx.x * 256 + threadIdx.x;  // chunk index (8 elements)
  const float* src;
  ushort* dst;
  int j;
  if (i < 262144)      { src = X;  dst = Xb;  j = i; }
  else if (i < 393216) { src = Wq; dst = Wqb; j = i - 262144; }
  else if (i < 524288) { src = Wk; dst = Wkb; j = i - 393216; }
  else if (i < 655360) { src = Wv; dst = Wvb; j = i - 524288; }
  else                 { src = Wo; dst = Wob; j = i - 655360; }
  float4 a = *reinterpret_cast<const float4*>(src + j * 8);
  float4 b = *reinterpret_cast<const float4*>(src + j * 8 + 4);
  *reinterpret_cast<uint4*>(dst + j * 8) = rne8(a, b);
}

// ---------------------------------------------------------------------------
// cos/sin table
// ---------------------------------------------------------------------------
__global__ __launch_bounds__(64) void k_cs(float* __restrict__ cs) {
  int s = blockIdx.x * 2 + (threadIdx.x >> 5);
  int p = threadIdx.x & 31;
  float invf = powf(10000.0f, (-2.0f * p) / 64.0f);
  float sn, c;
  sincosf((float)s * invf, &sn, &c);
  cs[s * 64 + 2 * p] = c;
  cs[s * 64 + 2 * p + 1] = sn;
}

// ---------------------------------------------------------------------------
// A[h,t,i] = (1/8) * sum_j proj[h,j] * tpl_norm[h,t,(i-j) mod 64]  -> hi/lo bf16
// ---------------------------------------------------------------------------
__global__ __launch_bounds__(64) void k_prep_A(const float* __restrict__ tpl,
                                               const float* __restrict__ proj,
                                               ushort* __restrict__ Ahh,
                                               ushort* __restrict__ Ahl) {
  int ht = blockIdx.x;
  int h = ht >> 5;
  int lane = threadIdx.x;
  float tv = tpl[ht * 64 + lane];
  float ss = tv * tv;
#pragma unroll
  for (int off = 1; off < 64; off <<= 1) ss += __shfl_xor(ss, off);
  float rn = 1.0f / fmaxf(sqrtf(ss), 1e-12f);
  __shared__ float tn[64];
  tn[lane] = tv * rn;
  __syncthreads();
  float acc = 0.f;
#pragma unroll
  for (int j = 0; j < 64; ++j) acc += proj[h * 64 + j] * tn[(lane - j) & 63];
  float v = acc * 0.125f;
  uint u = __builtin_bit_cast(uint, v);
  uint hi = u >> 16;
  float fh = __builtin_bit_cast(float, u & 0xffff0000u);
  uint lo = __builtin_bit_cast(uint, v - fh) >> 16;
  Ahh[ht * 64 + lane] = (ushort)hi;
  Ahl[ht * 64 + lane] = (ushort)lo;
}

// ---------------------------------------------------------------------------
// QKV GEMM, all-bf16 inputs. Tile 128x64, BK=64, 4 waves, wave tile 64x32.
// Epilogues (validated): z<2 RoPE+signature; z==2 transposed-bf16 V store.
// ---------------------------------------------------------------------------
__global__ __launch_bounds__(256) void k_qkv(
    const ushort* __restrict__ Xb,
    const ushort* __restrict__ Wqb, const ushort* __restrict__ Wkb,
    const ushort* __restrict__ Wvb,
    const ushort* __restrict__ Ahh, const ushort* __restrict__ Ahl,
    const float* __restrict__ cs,
    ushort* __restrict__ Qs, ushort* __restrict__ Ks,
    ushort* __restrict__ Vt) {
  // union: A bf16 [128][64] 16KB @0, B bf16 [64][64] 8KB @16384 | dmp f32[128][68]
  __shared__ __align__(16) char smem[34816];

  const int z = blockIdx.z;
  const ushort* Wm = (z == 0) ? Wqb : (z == 1) ? Wkb : Wvb;
  const int m0 = blockIdx.y * 128;
  const int n0 = blockIdx.x * 64;
  const int h = blockIdx.x;

  const int tid = threadIdx.x;
  const int l = tid & 63;
  const int wid = tid >> 6;
  const int wr = wid >> 1, wc = wid & 1;
  const int l31 = l & 31, lhi = l >> 5;

  const int arow = tid >> 1;           // 0..127
  const int acol = (tid & 1) * 4;      // chunk base 0 or 4
  const int brow = tid >> 2;           // 0..63
  const int bcol = (tid & 3) * 2;      // chunk base 0,2,4,6

  f32x16 acc0 = 0.0f, acc1 = 0.0f;

  for (int k0 = 0; k0 < 1024; k0 += 64) {
    uint4 a[4], b[2];
    {
      const ushort* ap = Xb + (size_t)(m0 + arow) * 1024 + k0 + acol * 8;
#pragma unroll
      for (int i = 0; i < 4; ++i)
        a[i] = *reinterpret_cast<const uint4*>(ap + i * 8);
      const ushort* bp = Wm + (size_t)(n0 + brow) * 1024 + k0 + bcol * 8;
#pragma unroll
      for (int i = 0; i < 2; ++i)
        b[i] = *reinterpret_cast<const uint4*>(bp + i * 8);
    }
    __syncthreads();
#pragma unroll
    for (int i = 0; i < 4; ++i) {
      int chk = (acol + i) ^ (arow & 7);
      *reinterpret_cast<uint4*>(smem + arow * 128 + chk * 16) = a[i];
    }
#pragma unroll
    for (int i = 0; i < 2; ++i) {
      int chk = (bcol + i) ^ (brow & 7);
      *reinterpret_cast<uint4*>(smem + 16384 + brow * 128 + chk * 16) = b[i];
    }
    __syncthreads();

#pragma unroll
    for (int kst = 0; kst < 4; ++kst) {
      FragU ah0, ah1, bh;
      {
        int row = wr * 64 + l31;
        int chk = (kst * 2 + lhi) ^ (row & 7);
        ah0.q = *reinterpret_cast<const uint4*>(smem + row * 128 + chk * 16);
      }
      {
        int row = wr * 64 + 32 + l31;
        int chk = (kst * 2 + lhi) ^ (row & 7);
        ah1.q = *reinterpret_cast<const uint4*>(smem + row * 128 + chk * 16);
      }
      {
        int br = wc * 32 + l31;
        int chk = (kst * 2 + lhi) ^ (br & 7);
        bh.q = *reinterpret_cast<const uint4*>(smem + 16384 + br * 128 + chk * 16);
      }
      acc0 = MFMA(ah0.v, bh.v, acc0);
      acc1 = MFMA(ah1.v, bh.v, acc1);
    }
  }

  if (z == 2) {
    int d = wc * 32 + l31;
#pragma unroll
    for (int fm = 0; fm < 2; ++fm) {
      const f32x16& a = fm ? acc1 : acc0;
#pragma unroll
      for (int j = 0; j < 16; ++j) {
        int rl = fm * 32 + (j & 3) + ((j >> 2) & 3) * 8 + 4 * lhi;
        int m = m0 + wr * 64 + rl;
        int b = m >> 10, s = m & 1023;
        Vt[((size_t)((b * 16 + h) * 64 + d)) * 1024 + s] = (ushort)rne16(a[j]);
      }
    }
    return;
  }

  ushort* Sig = (z == 0) ? Qs : Ks;
  float* dmp = reinterpret_cast<float*>(smem);  // [128][68] f32
  __syncthreads();
#pragma unroll
  for (int fm = 0; fm < 2; ++fm) {
    const f32x16& a = fm ? acc1 : acc0;
#pragma unroll
    for (int j = 0; j < 16; ++j) {
      int rl = fm * 32 + (j & 3) + ((j >> 2) & 3) * 8 + 4 * lhi;
      dmp[(wr * 64 + rl) * 68 + wc * 32 + l31] = a[j];
    }
  }
  __syncthreads();

  int srow = wr * 64 + wc * 32 + l31;
  int sq = (m0 + srow) & 1023;
  f32x16 sacc = 0.0f;
#pragma unroll
  for (int kst = 0; kst < 4; ++kst) {
    const float* dp = &dmp[srow * 68 + kst * 16 + lhi * 8];
    float4 x0 = *reinterpret_cast<const float4*>(dp);
    float4 x1 = *reinterpret_cast<const float4*>(dp + 4);
    const float* cp = &cs[sq * 64 + kst * 16 + lhi * 8];
    float4 c0 = *reinterpret_cast<const float4*>(cp);
    float4 c1 = *reinterpret_cast<const float4*>(cp + 4);
    float r[8];
    r[0] = x0.x * c0.x - x0.y * c0.y;
    r[1] = x0.x * c0.y + x0.y * c0.x;
    r[2] = x0.z * c0.z - x0.w * c0.w;
    r[3] = x0.z * c0.w + x0.w * c0.z;
    r[4] = x1.x * c1.x - x1.y * c1.y;
    r[5] = x1.x * c1.y + x1.y * c1.x;
    r[6] = x1.z * c1.z - x1.w * c1.w;
    r[7] = x1.z * c1.w + x1.w * c1.z;
    FragU ah, al;
    split8a(r, ah.q, al.q);
    size_t boff = ((size_t)(h * 32 + l31) * 64 + kst * 16 + lhi * 8);
    FragU bh, bl;
    bh.q = *reinterpret_cast<const uint4*>(Ahh + boff);
    bl.q = *reinterpret_cast<const uint4*>(Ahl + boff);
    sacc = MFMA(al.v, bh.v, sacc);
    sacc = MFMA(ah.v, bl.v, sacc);
    sacc = MFMA(ah.v, bh.v, sacc);
  }
#pragma unroll
  for (int j = 0; j < 16; ++j) {
    float v = sacc[j];
    float ss = v * v;
    ss += __shfl_xor(ss, 1);
    ss += __shfl_xor(ss, 2);
    ss += __shfl_xor(ss, 4);
    ss += __shfl_xor(ss, 8);
    ss += __shfl_xor(ss, 16);
    float rn = 1.0f / fmaxf(sqrtf(ss), 1e-12f);
    int rl = (j & 3) + ((j >> 2) & 3) * 8 + 4 * lhi;
    int m = m0 + wr * 64 + wc * 32 + rl;
    int bb = m >> 10, s2 = m & 1023;
    Sig[(((size_t)(bb * 16 + h)) * 1024 + s2) * 32 + l31] =
        (ushort)rne16(v * rn);
  }
}

// ---------------------------------------------------------------------------
// MFMA attention (validated round-5).
// ---------------------------------------------------------------------------
__global__ __launch_bounds__(128) void k_attn(const ushort* __restrict__ Qs,
                                              const ushort* __restrict__ Ks,
                                              const ushort* __restrict__ Vt,
                                              ushort* __restrict__ O) {
  __shared__ ushort plds[2][32][68];

  const int tid = threadIdx.x;
  const int l = tid & 63;
  const int wid = tid >> 6;
  const int l31 = l & 31, lhi = l >> 5;
  const int bh = blockIdx.y;
  const int q0 = blockIdx.x * 64 + wid * 32;

  FragU aq0, aq1;
  {
    const ushort* qp = Qs + ((size_t)bh * 1024 + q0 + l31) * 32 + lhi * 8;
    aq0.q = *reinterpret_cast<const uint4*>(qp);
    aq1.q = *reinterpret_cast<const uint4*>(qp + 16);
  }

  const ushort* kbase = Ks + (size_t)bh * 1024 * 32;
  const ushort* vbase = Vt + (size_t)bh * 64 * 1024;

  f32x16 oacc0 = 0.0f, oacc1 = 0.0f;
  float pden[16];
#pragma unroll
  for (int r = 0; r < 16; ++r) pden[r] = 0.f;

  for (int kt = 0; kt < 16; ++kt) {
    const int k0 = kt * 64;
    f32x16 sacc[2];
    sacc[0] = 0.0f;
    sacc[1] = 0.0f;
#pragma unroll
    for (int nt = 0; nt < 2; ++nt) {
      const ushort* kp = kbase + (size_t)(k0 + nt * 32 + l31) * 32 + lhi * 8;
      FragU b0, b1;
      b0.q = *reinterpret_cast<const uint4*>(kp);
      b1.q = *reinterpret_cast<const uint4*>(kp + 16);
      sacc[nt] = MFMA(aq0.v, b0.v, sacc[nt]);
      sacc[nt] = MFMA(aq1.v, b1.v, sacc[nt]);
    }
#pragma unroll
    for (int nt = 0; nt < 2; ++nt) {
#pragma unroll
      for (int r = 0; r < 16; ++r) {
        float e = __expf(sacc[nt][r] * SCALE_F);
        pden[r] += e;
        int q = (r & 3) + ((r >> 2) << 3) + 4 * lhi;
        plds[wid][q][nt * 32 + l31] = (ushort)rne16(e);
      }
    }
    __builtin_amdgcn_wave_barrier();
#pragma unroll
    for (int kst = 0; kst < 4; ++kst) {
      FragU ap;
      const ushort* pp = &plds[wid][l31][kst * 16 + lhi * 8];
      uint2 plo = *reinterpret_cast<const uint2*>(pp);
      uint2 phi = *reinterpret_cast<const uint2*>(pp + 4);
      ap.q = make_uint4(plo.x, plo.y, phi.x, phi.y);
      FragU bv0, bv1;
      const ushort* vp0 = vbase + (size_t)l31 * 1024 + k0 + kst * 16 + lhi * 8;
      bv0.q = *reinterpret_cast<const uint4*>(vp0);
      bv1.q = *reinterpret_cast<const uint4*>(vp0 + 32 * 1024);
      oacc0 = MFMA(ap.v, bv0.v, oacc0);
      oacc1 = MFMA(ap.v, bv1.v, oacc1);
    }
  }

#pragma unroll
  for (int r = 0; r < 16; ++r) {
    float s = pden[r];
    s += __shfl_xor(s, 1);
    s += __shfl_xor(s, 2);
    s += __shfl_xor(s, 4);
    s += __shfl_xor(s, 8);
    s += __shfl_xor(s, 16);
    pden[r] = 1.0f / s;
  }

  const int b = bh >> 4, h = bh & 15;
#pragma unroll
  for (int r = 0; r < 16; ++r) {
    int q = q0 + (r & 3) + ((r >> 2) << 3) + 4 * lhi;
    size_t row = ((size_t)b * 1024 + q) * 1024 + h * 64;
    O[row + l31] = (ushort)rne16(oacc0[r] * pden[r]);
    O[row + 32 + l31] = (ushort)rne16(oacc1[r] * pden[r]);
  }
}

// ---------------------------------------------------------------------------
// Final projection (validated round-5): 64x64 tile, all-bf16.
// ---------------------------------------------------------------------------
__global__ __launch_bounds__(256) void k_final(const ushort* __restrict__ Xb,
                                               const ushort* __restrict__ Wb,
                                               float* __restrict__ Y) {
  __shared__ __align__(16) char smem[8192];

  const int m0 = blockIdx.y * 64;
  const int n0 = blockIdx.x * 64;
  const int tid = threadIdx.x;
  const int l = tid & 63;
  const int wid = tid >> 6;
  const int wr = wid >> 1, wc = wid & 1;
  const int l31 = l & 31, lhi = l >> 5;
  const int sr = tid >> 2;
  const int sc = tid & 3;

  f32x16 acc = 0.0f;

  for (int k0 = 0; k0 < 1024; k0 += 32) {
    uint4 av = *reinterpret_cast<const uint4*>(
        Xb + (size_t)(m0 + sr) * 1024 + k0 + sc * 8);
    uint4 bv = *reinterpret_cast<const uint4*>(
        Wb + (size_t)(n0 + sr) * 1024 + k0 + sc * 8);
    __syncthreads();
    int off = sr * 64 + ((sc ^ ((sr >> 1) & 3)) << 4);
    *reinterpret_cast<uint4*>(smem + off) = av;
    *reinterpret_cast<uint4*>(smem + 4096 + off) = bv;
    __syncthreads();

#pragma unroll
    for (int kst = 0; kst < 2; ++kst) {
      FragU ah, bh;
      int row = wr * 32 + l31;
      int cc = (kst * 2 + lhi) ^ ((row >> 1) & 3);
      ah.q = *reinterpret_cast<const uint4*>(smem + row * 64 + cc * 16);
      int brow = wc * 32 + l31;
      int bcc = (kst * 2 + lhi) ^ ((brow >> 1) & 3);
      bh.q = *reinterpret_cast<const uint4*>(smem + 4096 + brow * 64 + bcc * 16);
      acc = MFMA(ah.v, bh.v, acc);
    }
  }

#pragma unroll
  for (int j = 0; j < 16; ++j) {
    int rl = (j & 3) + ((j >> 2) & 3) * 8 + 4 * lhi;
    int m = m0 + wr * 32 + rl;
    Y[(size_t)m * 1024 + n0 + wc * 32 + l31] = acc[j];
  }
}

// ---------------------------------------------------------------------------
extern "C" void kernel_launch(void* const* d_in, const int* in_sizes, int n_in,
                              void* d_out, int out_size, void* d_ws,
                              size_t ws_size, hipStream_t stream) {
  const float* x = (const float*)d_in[0];
  const float* Wq = (const float*)d_in[1];
  const float* Wk = (const float*)d_in[2];
  const float* Wv = (const float*)d_in[3];
  const float* Wo = (const float*)d_in[4];
  const float* tpl = (const float*)d_in[5];
  const float* proj = (const float*)d_in[6];
  float* out = (float*)d_out;

  char* ws = (char*)d_ws;
  size_t off = 0;
  auto alloc = [&](size_t bytes) {
    void* p = ws + off;
    off += (bytes + 255) & ~(size_t)255;
    return p;
  };
  // ws (peak ~14.5 MB):
  //  [cs 256K | Ahh 64K | Ahl 64K | Wqb 2M | Wkb 2M]  <- obuf (4MB) aliases
  //  [Wob 2M | qs 2M | ks 2M | vt 4M]
  float* cs = (float*)alloc((size_t)1024 * 64 * 4);
  ushort* Ahh = (ushort*)alloc((size_t)16 * 32 * 64 * 2);
  ushort* Ahl = (ushort*)alloc((size_t)16 * 32 * 64 * 2);
  ushort* Wqb = (ushort*)alloc((size_t)1024 * 1024 * 2);
  ushort* Wkb = (ushort*)alloc((size_t)1024 * 1024 * 2);
  ushort* Wob = (ushort*)alloc((size_t)1024 * 1024 * 2);
  ushort* qs = (ushort*)alloc((size_t)32 * 1024 * 32 * 2);
  ushort* ks = (ushort*)alloc((size_t)32 * 1024 * 32 * 2);
  ushort* vt = (ushort*)alloc((size_t)32 * 64 * 1024 * 2);
  ushort* obuf = (ushort*)ws;  // aliases [cs..Wkb] (dead after k_qkv)

  // d_out as scratch (fully rewritten by k_final): Xb 4MB | Wvb 2MB
  ushort* Xb = (ushort*)d_out;
  ushort* Wvb = (ushort*)((char*)d_out + (size_t)4 * 1024 * 1024);

  k_cvtall<<<dim3(3072), dim3(256), 0, stream>>>(x, Wq, Wk, Wv, Wo, Xb, Wqb,
                                                 Wkb, Wvb, Wob);
  k_cs<<<dim3(512), dim3(64), 0, stream>>>(cs);
  k_prep_A<<<dim3(512), dim3(64), 0, stream>>>(tpl, proj, Ahh, Ahl);
  k_qkv<<<dim3(16, 16, 3), dim3(256), 0, stream>>>(Xb, Wqb, Wkb, Wvb, Ahh, Ahl,
                                                   cs, qs, ks, vt);
  k_attn<<<dim3(16, 32), dim3(128), 0, stream>>>(qs, ks, vt, obuf);
  k_final<<<dim3(16, 32), dim3(256), 0, stream>>>(obuf, Wob, out);
}

// Round 7
// 137.019 us; speedup vs baseline: 1.1511x; 1.1511x over previous
//
#include <hip/hip_runtime.h>
#include <math.h>

#define S_ 1024
#define T_ 32
#define SCALE_F 0.7071067811865476f

typedef unsigned int uint;
typedef unsigned short ushort;
typedef __bf16 bf16x8 __attribute__((ext_vector_type(8)));
typedef float f32x16 __attribute__((ext_vector_type(16)));

union FragU { uint4 q; bf16x8 v; };

#define MFMA(a, b, c) __builtin_amdgcn_mfma_f32_32x32x16_bf16((a), (b), (c), 0, 0, 0)

__device__ __forceinline__ uint rne16(float f) {
  uint u = __builtin_bit_cast(uint, f);
  u += 0x7fffu + ((u >> 16) & 1u);
  return u >> 16;
}

__device__ __forceinline__ void split8a(const float* f, uint4& hi, uint4& lo) {
  uint h[8], m[8];
#pragma unroll
  for (int i = 0; i < 8; ++i) {
    uint u = __builtin_bit_cast(uint, f[i]);
    h[i] = u >> 16;
    float fh = __builtin_bit_cast(float, u & 0xffff0000u);
    m[i] = __builtin_bit_cast(uint, f[i] - fh) >> 16;
  }
  hi = make_uint4(h[0] | (h[1] << 16), h[2] | (h[3] << 16),
                  h[4] | (h[5] << 16), h[6] | (h[7] << 16));
  lo = make_uint4(m[0] | (m[1] << 16), m[2] | (m[3] << 16),
                  m[4] | (m[5] << 16), m[6] | (m[7] << 16));
}

__device__ __forceinline__ uint4 rne8(const float4& A, const float4& B) {
  float f[8] = {A.x, A.y, A.z, A.w, B.x, B.y, B.z, B.w};
  uint h[8];
#pragma unroll
  for (int i = 0; i < 8; ++i) h[i] = rne16(f[i]);
  return make_uint4(h[0] | (h[1] << 16), h[2] | (h[3] << 16),
                    h[4] | (h[5] << 16), h[6] | (h[7] << 16));
}

// ---------------------------------------------------------------------------
// Bulk f32->bf16: X (2M el), Wq, Wk, Wv, Wo (1M each). 8 el/thread.
// ---------------------------------------------------------------------------
__global__ __launch_bounds__(256) void k_cvtall(
    const float* __restrict__ X, const float* __restrict__ Wq,
    const float* __restrict__ Wk, const float* __restrict__ Wv,
    const float* __restrict__ Wo, ushort* __restrict__ Xb,
    ushort* __restrict__ Wqb, ushort* __restrict__ Wkb,
    ushort* __restrict__ Wvb, ushort* __restrict__ Wob) {
  int i = blockIdx.x * 256 + threadIdx.x;  // chunk index (8 elements)
  const float* src;
  ushort* dst;
  int j;
  if (i < 262144)      { src = X;  dst = Xb;  j = i; }
  else if (i < 393216) { src = Wq; dst = Wqb; j = i - 262144; }
  else if (i < 524288) { src = Wk; dst = Wkb; j = i - 393216; }
  else if (i < 655360) { src = Wv; dst = Wvb; j = i - 524288; }
  else                 { src = Wo; dst = Wob; j = i - 655360; }
  float4 a = *reinterpret_cast<const float4*>(src + j * 8);
  float4 b = *reinterpret_cast<const float4*>(src + j * 8 + 4);
  *reinterpret_cast<uint4*>(dst + j * 8) = rne8(a, b);
}

// ---------------------------------------------------------------------------
// cos/sin table
// ---------------------------------------------------------------------------
__global__ __launch_bounds__(64) void k_cs(float* __restrict__ cs) {
  int s = blockIdx.x * 2 + (threadIdx.x >> 5);
  int p = threadIdx.x & 31;
  float invf = powf(10000.0f, (-2.0f * p) / 64.0f);
  float sn, c;
  sincosf((float)s * invf, &sn, &c);
  cs[s * 64 + 2 * p] = c;
  cs[s * 64 + 2 * p + 1] = sn;
}

// ---------------------------------------------------------------------------
// A[h,t,i] = (1/8) * sum_j proj[h,j] * tpl_norm[h,t,(i-j) mod 64]  -> hi/lo bf16
// ---------------------------------------------------------------------------
__global__ __launch_bounds__(64) void k_prep_A(const float* __restrict__ tpl,
                                               const float* __restrict__ proj,
                                               ushort* __restrict__ Ahh,
                                               ushort* __restrict__ Ahl) {
  int ht = blockIdx.x;
  int h = ht >> 5;
  int lane = threadIdx.x;
  float tv = tpl[ht * 64 + lane];
  float ss = tv * tv;
#pragma unroll
  for (int off = 1; off < 64; off <<= 1) ss += __shfl_xor(ss, off);
  float rn = 1.0f / fmaxf(sqrtf(ss), 1e-12f);
  __shared__ float tn[64];
  tn[lane] = tv * rn;
  __syncthreads();
  float acc = 0.f;
#pragma unroll
  for (int j = 0; j < 64; ++j) acc += proj[h * 64 + j] * tn[(lane - j) & 63];
  float v = acc * 0.125f;
  uint u = __builtin_bit_cast(uint, v);
  uint hi = u >> 16;
  float fh = __builtin_bit_cast(float, u & 0xffff0000u);
  uint lo = __builtin_bit_cast(uint, v - fh) >> 16;
  Ahh[ht * 64 + lane] = (ushort)hi;
  Ahl[ht * 64 + lane] = (ushort)lo;
}

// ---------------------------------------------------------------------------
// QKV GEMM: round-5 validated skeleton (tile 128x64, BK=32, 64B LDS rows,
// ((row>>1)&3) XOR swizzle), staging = direct bf16 uint4 copies.
// z<2: single-product + RoPE/signature epilogue (validated, verbatim).
// z==2: transposed-bf16 V store (validated, verbatim).
// ---------------------------------------------------------------------------
__global__ __launch_bounds__(256) void k_qkv(
    const ushort* __restrict__ Xb,
    const ushort* __restrict__ Wqb, const ushort* __restrict__ Wkb,
    const ushort* __restrict__ Wvb,
    const ushort* __restrict__ Ahh, const ushort* __restrict__ Ahl,
    const float* __restrict__ cs,
    ushort* __restrict__ Qs, ushort* __restrict__ Ks,
    ushort* __restrict__ Vt) {
  // A bf16 [128][32] 8KB @0, B bf16 [64][32] 4KB @8192 | dmp f32 [128][68]
  __shared__ __align__(16) char smem[34816];

  const int z = blockIdx.z;
  const ushort* Wm = (z == 0) ? Wqb : (z == 1) ? Wkb : Wvb;
  const int m0 = blockIdx.y * 128;
  const int n0 = blockIdx.x * 64;
  const int h = blockIdx.x;

  const int tid = threadIdx.x;
  const int l = tid & 63;
  const int wid = tid >> 6;
  const int wr = wid >> 1, wc = wid & 1;
  const int l31 = l & 31, lhi = l >> 5;

  const int sr = tid >> 2;   // staging row 0..63
  const int sc = tid & 3;    // staging 16B col 0..3

  f32x16 acc0 = 0.0f, acc1 = 0.0f;

  for (int k0 = 0; k0 < 1024; k0 += 32) {
    uint4 a[2], b;
#pragma unroll
    for (int sl = 0; sl < 2; ++sl)
      a[sl] = *reinterpret_cast<const uint4*>(
          Xb + (size_t)(m0 + sr + 64 * sl) * 1024 + k0 + sc * 8);
    b = *reinterpret_cast<const uint4*>(
        Wm + (size_t)(n0 + sr) * 1024 + k0 + sc * 8);
    __syncthreads();
#pragma unroll
    for (int sl = 0; sl < 2; ++sl) {
      int row = sr + 64 * sl;
      int off = row * 64 + ((sc ^ ((row >> 1) & 3)) << 4);
      *reinterpret_cast<uint4*>(smem + off) = a[sl];
    }
    {
      int off = sr * 64 + ((sc ^ ((sr >> 1) & 3)) << 4);
      *reinterpret_cast<uint4*>(smem + 8192 + off) = b;
    }
    __syncthreads();

#pragma unroll
    for (int kst = 0; kst < 2; ++kst) {
      FragU ah0, ah1, bh;
      {
        int row = wr * 64 + l31;
        int cc = (kst * 2 + lhi) ^ ((row >> 1) & 3);
        ah0.q = *reinterpret_cast<const uint4*>(smem + row * 64 + cc * 16);
      }
      {
        int row = wr * 64 + 32 + l31;
        int cc = (kst * 2 + lhi) ^ ((row >> 1) & 3);
        ah1.q = *reinterpret_cast<const uint4*>(smem + row * 64 + cc * 16);
      }
      {
        int brow = wc * 32 + l31;
        int bcc = (kst * 2 + lhi) ^ ((brow >> 1) & 3);
        bh.q = *reinterpret_cast<const uint4*>(smem + 8192 + brow * 64 + bcc * 16);
      }
      acc0 = MFMA(ah0.v, bh.v, acc0);
      acc1 = MFMA(ah1.v, bh.v, acc1);
    }
  }

  if (z == 2) {
    int d = wc * 32 + l31;
#pragma unroll
    for (int fm = 0; fm < 2; ++fm) {
      const f32x16& a = fm ? acc1 : acc0;
#pragma unroll
      for (int j = 0; j < 16; ++j) {
        int rl = fm * 32 + (j & 3) + ((j >> 2) & 3) * 8 + 4 * lhi;
        int m = m0 + wr * 64 + rl;
        int b = m >> 10, s = m & 1023;
        Vt[((size_t)((b * 16 + h) * 64 + d)) * 1024 + s] = (ushort)rne16(a[j]);
      }
    }
    return;
  }

  ushort* Sig = (z == 0) ? Qs : Ks;
  float* dmp = reinterpret_cast<float*>(smem);  // [128][68] f32
  __syncthreads();
#pragma unroll
  for (int fm = 0; fm < 2; ++fm) {
    const f32x16& a = fm ? acc1 : acc0;
#pragma unroll
    for (int j = 0; j < 16; ++j) {
      int rl = fm * 32 + (j & 3) + ((j >> 2) & 3) * 8 + 4 * lhi;
      dmp[(wr * 64 + rl) * 68 + wc * 32 + l31] = a[j];
    }
  }
  __syncthreads();

  int srow = wr * 64 + wc * 32 + l31;
  int sq = (m0 + srow) & 1023;
  f32x16 sacc = 0.0f;
#pragma unroll
  for (int kst = 0; kst < 4; ++kst) {
    const float* dp = &dmp[srow * 68 + kst * 16 + lhi * 8];
    float4 x0 = *reinterpret_cast<const float4*>(dp);
    float4 x1 = *reinterpret_cast<const float4*>(dp + 4);
    const float* cp = &cs[sq * 64 + kst * 16 + lhi * 8];
    float4 c0 = *reinterpret_cast<const float4*>(cp);
    float4 c1 = *reinterpret_cast<const float4*>(cp + 4);
    float r[8];
    r[0] = x0.x * c0.x - x0.y * c0.y;
    r[1] = x0.x * c0.y + x0.y * c0.x;
    r[2] = x0.z * c0.z - x0.w * c0.w;
    r[3] = x0.z * c0.w + x0.w * c0.z;
    r[4] = x1.x * c1.x - x1.y * c1.y;
    r[5] = x1.x * c1.y + x1.y * c1.x;
    r[6] = x1.z * c1.z - x1.w * c1.w;
    r[7] = x1.z * c1.w + x1.w * c1.z;
    FragU ah, al;
    split8a(r, ah.q, al.q);
    size_t boff = ((size_t)(h * 32 + l31) * 64 + kst * 16 + lhi * 8);
    FragU bh, bl;
    bh.q = *reinterpret_cast<const uint4*>(Ahh + boff);
    bl.q = *reinterpret_cast<const uint4*>(Ahl + boff);
    sacc = MFMA(al.v, bh.v, sacc);
    sacc = MFMA(ah.v, bl.v, sacc);
    sacc = MFMA(ah.v, bh.v, sacc);
  }
#pragma unroll
  for (int j = 0; j < 16; ++j) {
    float v = sacc[j];
    float ss = v * v;
    ss += __shfl_xor(ss, 1);
    ss += __shfl_xor(ss, 2);
    ss += __shfl_xor(ss, 4);
    ss += __shfl_xor(ss, 8);
    ss += __shfl_xor(ss, 16);
    float rn = 1.0f / fmaxf(sqrtf(ss), 1e-12f);
    int rl = (j & 3) + ((j >> 2) & 3) * 8 + 4 * lhi;
    int m = m0 + wr * 64 + wc * 32 + rl;
    int bb = m >> 10, s2 = m & 1023;
    Sig[(((size_t)(bb * 16 + h)) * 1024 + s2) * 32 + l31] =
        (ushort)rne16(v * rn);
  }
}

// ---------------------------------------------------------------------------
// MFMA attention (validated round-5).
// ---------------------------------------------------------------------------
__global__ __launch_bounds__(128) void k_attn(const ushort* __restrict__ Qs,
                                              const ushort* __restrict__ Ks,
                                              const ushort* __restrict__ Vt,
                                              ushort* __restrict__ O) {
  __shared__ ushort plds[2][32][68];

  const int tid = threadIdx.x;
  const int l = tid & 63;
  const int wid = tid >> 6;
  const int l31 = l & 31, lhi = l >> 5;
  const int bh = blockIdx.y;
  const int q0 = blockIdx.x * 64 + wid * 32;

  FragU aq0, aq1;
  {
    const ushort* qp = Qs + ((size_t)bh * 1024 + q0 + l31) * 32 + lhi * 8;
    aq0.q = *reinterpret_cast<const uint4*>(qp);
    aq1.q = *reinterpret_cast<const uint4*>(qp + 16);
  }

  const ushort* kbase = Ks + (size_t)bh * 1024 * 32;
  const ushort* vbase = Vt + (size_t)bh * 64 * 1024;

  f32x16 oacc0 = 0.0f, oacc1 = 0.0f;
  float pden[16];
#pragma unroll
  for (int r = 0; r < 16; ++r) pden[r] = 0.f;

  for (int kt = 0; kt < 16; ++kt) {
    const int k0 = kt * 64;
    f32x16 sacc[2];
    sacc[0] = 0.0f;
    sacc[1] = 0.0f;
#pragma unroll
    for (int nt = 0; nt < 2; ++nt) {
      const ushort* kp = kbase + (size_t)(k0 + nt * 32 + l31) * 32 + lhi * 8;
      FragU b0, b1;
      b0.q = *reinterpret_cast<const uint4*>(kp);
      b1.q = *reinterpret_cast<const uint4*>(kp + 16);
      sacc[nt] = MFMA(aq0.v, b0.v, sacc[nt]);
      sacc[nt] = MFMA(aq1.v, b1.v, sacc[nt]);
    }
#pragma unroll
    for (int nt = 0; nt < 2; ++nt) {
#pragma unroll
      for (int r = 0; r < 16; ++r) {
        float e = __expf(sacc[nt][r] * SCALE_F);
        pden[r] += e;
        int q = (r & 3) + ((r >> 2) << 3) + 4 * lhi;
        plds[wid][q][nt * 32 + l31] = (ushort)rne16(e);
      }
    }
    __builtin_amdgcn_wave_barrier();
#pragma unroll
    for (int kst = 0; kst < 4; ++kst) {
      FragU ap;
      const ushort* pp = &plds[wid][l31][kst * 16 + lhi * 8];
      uint2 plo = *reinterpret_cast<const uint2*>(pp);
      uint2 phi = *reinterpret_cast<const uint2*>(pp + 4);
      ap.q = make_uint4(plo.x, plo.y, phi.x, phi.y);
      FragU bv0, bv1;
      const ushort* vp0 = vbase + (size_t)l31 * 1024 + k0 + kst * 16 + lhi * 8;
      bv0.q = *reinterpret_cast<const uint4*>(vp0);
      bv1.q = *reinterpret_cast<const uint4*>(vp0 + 32 * 1024);
      oacc0 = MFMA(ap.v, bv0.v, oacc0);
      oacc1 = MFMA(ap.v, bv1.v, oacc1);
    }
  }

#pragma unroll
  for (int r = 0; r < 16; ++r) {
    float s = pden[r];
    s += __shfl_xor(s, 1);
    s += __shfl_xor(s, 2);
    s += __shfl_xor(s, 4);
    s += __shfl_xor(s, 8);
    s += __shfl_xor(s, 16);
    pden[r] = 1.0f / s;
  }

  const int b = bh >> 4, h = bh & 15;
#pragma unroll
  for (int r = 0; r < 16; ++r) {
    int q = q0 + (r & 3) + ((r >> 2) << 3) + 4 * lhi;
    size_t row = ((size_t)b * 1024 + q) * 1024 + h * 64;
    O[row + l31] = (ushort)rne16(oacc0[r] * pden[r]);
    O[row + 32 + l31] = (ushort)rne16(oacc1[r] * pden[r]);
  }
}

// ---------------------------------------------------------------------------
// Final projection (validated round-5): 64x64 tile, all-bf16.
// ---------------------------------------------------------------------------
__global__ __launch_bounds__(256) void k_final(const ushort* __restrict__ Xb,
                                               const ushort* __restrict__ Wb,
                                               float* __restrict__ Y) {
  __shared__ __align__(16) char smem[8192];

  const int m0 = blockIdx.y * 64;
  const int n0 = blockIdx.x * 64;
  const int tid = threadIdx.x;
  const int l = tid & 63;
  const int wid = tid >> 6;
  const int wr = wid >> 1, wc = wid & 1;
  const int l31 = l & 31, lhi = l >> 5;
  const int sr = tid >> 2;
  const int sc = tid & 3;

  f32x16 acc = 0.0f;

  for (int k0 = 0; k0 < 1024; k0 += 32) {
    uint4 av = *reinterpret_cast<const uint4*>(
        Xb + (size_t)(m0 + sr) * 1024 + k0 + sc * 8);
    uint4 bv = *reinterpret_cast<const uint4*>(
        Wb + (size_t)(n0 + sr) * 1024 + k0 + sc * 8);
    __syncthreads();
    int off = sr * 64 + ((sc ^ ((sr >> 1) & 3)) << 4);
    *reinterpret_cast<uint4*>(smem + off) = av;
    *reinterpret_cast<uint4*>(smem + 4096 + off) = bv;
    __syncthreads();

#pragma unroll
    for (int kst = 0; kst < 2; ++kst) {
      FragU ah, bh;
      int row = wr * 32 + l31;
      int cc = (kst * 2 + lhi) ^ ((row >> 1) & 3);
      ah.q = *reinterpret_cast<const uint4*>(smem + row * 64 + cc * 16);
      int brow = wc * 32 + l31;
      int bcc = (kst * 2 + lhi) ^ ((brow >> 1) & 3);
      bh.q = *reinterpret_cast<const uint4*>(smem + 4096 + brow * 64 + bcc * 16);
      acc = MFMA(ah.v, bh.v, acc);
    }
  }

#pragma unroll
  for (int j = 0; j < 16; ++j) {
    int rl = (j & 3) + ((j >> 2) & 3) * 8 + 4 * lhi;
    int m = m0 + wr * 32 + rl;
    Y[(size_t)m * 1024 + n0 + wc * 32 + l31] = acc[j];
  }
}

// ---------------------------------------------------------------------------
extern "C" void kernel_launch(void* const* d_in, const int* in_sizes, int n_in,
                              void* d_out, int out_size, void* d_ws,
                              size_t ws_size, hipStream_t stream) {
  const float* x = (const float*)d_in[0];
  const float* Wq = (const float*)d_in[1];
  const float* Wk = (const float*)d_in[2];
  const float* Wv = (const float*)d_in[3];
  const float* Wo = (const float*)d_in[4];
  const float* tpl = (const float*)d_in[5];
  const float* proj = (const float*)d_in[6];
  float* out = (float*)d_out;

  char* ws = (char*)d_ws;
  size_t off = 0;
  auto alloc = [&](size_t bytes) {
    void* p = ws + off;
    off += (bytes + 255) & ~(size_t)255;
    return p;
  };

  const size_t MB = 1024 * 1024;
  // Preferred (big-ws) layout, ~20.5 MB: everything ws-resident; obuf aliases
  // Xb (dead after k_qkv). Fallback (<21 MB ws): round-6-proven plan with
  // Xb/Wvb staged in d_out (fully rewritten by k_final) — deterministic.
  bool big = ws_size >= 22 * MB;

  ushort *Xb, *Wvb, *obuf;
  float* cs;
  ushort *Ahh, *Ahl, *Wqb, *Wkb, *Wob, *qs, *ks, *vt;

  if (big) {
    Xb = (ushort*)alloc(4 * MB);                 // bf16 X [2048][1024]
    cs = (float*)alloc((size_t)1024 * 64 * 4);
    Ahh = (ushort*)alloc((size_t)16 * 32 * 64 * 2);
    Ahl = (ushort*)alloc((size_t)16 * 32 * 64 * 2);
    Wqb = (ushort*)alloc(2 * MB);
    Wkb = (ushort*)alloc(2 * MB);
    Wvb = (ushort*)alloc(2 * MB);
    Wob = (ushort*)alloc(2 * MB);
    qs = (ushort*)alloc(2 * MB);
    ks = (ushort*)alloc(2 * MB);
    vt = (ushort*)alloc(4 * MB);
    obuf = Xb;  // Xb dead after k_qkv
  } else {
    cs = (float*)alloc((size_t)1024 * 64 * 4);
    Ahh = (ushort*)alloc((size_t)16 * 32 * 64 * 2);
    Ahl = (ushort*)alloc((size_t)16 * 32 * 64 * 2);
    Wqb = (ushort*)alloc(2 * MB);
    Wkb = (ushort*)alloc(2 * MB);
    Wob = (ushort*)alloc(2 * MB);
    qs = (ushort*)alloc(2 * MB);
    ks = (ushort*)alloc(2 * MB);
    vt = (ushort*)alloc(4 * MB);
    obuf = (ushort*)ws;  // aliases [cs..Wkb] (dead after k_qkv)
    Xb = (ushort*)d_out;
    Wvb = (ushort*)((char*)d_out + 4 * MB);
  }

  k_cvtall<<<dim3(3072), dim3(256), 0, stream>>>(x, Wq, Wk, Wv, Wo, Xb, Wqb,
                                                 Wkb, Wvb, Wob);
  k_cs<<<dim3(512), dim3(64), 0, stream>>>(cs);
  k_prep_A<<<dim3(512), dim3(64), 0, stream>>>(tpl, proj, Ahh, Ahl);
  k_qkv<<<dim3(16, 16, 3), dim3(256), 0, stream>>>(Xb, Wqb, Wkb, Wvb, Ahh, Ahl,
                                                   cs, qs, ks, vt);
  k_attn<<<dim3(16, 32), dim3(128), 0, stream>>>(qs, ks, vt, obuf);
  k_final<<<dim3(16, 32), dim3(256), 0, stream>>>(obuf, Wob, out);
}

// Round 8
// 100.665 us; speedup vs baseline: 1.5669x; 1.3611x over previous
//
#include <hip/hip_runtime.h>
#include <math.h>

#define S_ 1024
#define T_ 32
#define SCALE_F 0.7071067811865476f

typedef unsigned int uint;
typedef unsigned short ushort;
typedef __bf16 bf16x8 __attribute__((ext_vector_type(8)));
typedef float f32x16 __attribute__((ext_vector_type(16)));

union FragU { uint4 q; bf16x8 v; };

#define MFMA(a, b, c) __builtin_amdgcn_mfma_f32_32x32x16_bf16((a), (b), (c), 0, 0, 0)

__device__ __forceinline__ uint rne16(float f) {
  uint u = __builtin_bit_cast(uint, f);
  u += 0x7fffu + ((u >> 16) & 1u);
  return u >> 16;
}

__device__ __forceinline__ void split8a(const float* f, uint4& hi, uint4& lo) {
  uint h[8], m[8];
#pragma unroll
  for (int i = 0; i < 8; ++i) {
    uint u = __builtin_bit_cast(uint, f[i]);
    h[i] = u >> 16;
    float fh = __builtin_bit_cast(float, u & 0xffff0000u);
    m[i] = __builtin_bit_cast(uint, f[i] - fh) >> 16;
  }
  hi = make_uint4(h[0] | (h[1] << 16), h[2] | (h[3] << 16),
                  h[4] | (h[5] << 16), h[6] | (h[7] << 16));
  lo = make_uint4(m[0] | (m[1] << 16), m[2] | (m[3] << 16),
                  m[4] | (m[5] << 16), m[6] | (m[7] << 16));
}

__device__ __forceinline__ uint4 rne8(const float4& A, const float4& B) {
  float f[8] = {A.x, A.y, A.z, A.w, B.x, B.y, B.z, B.w};
  uint h[8];
#pragma unroll
  for (int i = 0; i < 8; ++i) h[i] = rne16(f[i]);
  return make_uint4(h[0] | (h[1] << 16), h[2] | (h[3] << 16),
                    h[4] | (h[5] << 16), h[6] | (h[7] << 16));
}

// ---------------------------------------------------------------------------
// Bulk f32->bf16: X (2M el), Wq, Wk, Wv, Wo (1M each). 8 el/thread.
// ---------------------------------------------------------------------------
__global__ __launch_bounds__(256) void k_cvtall(
    const float* __restrict__ X, const float* __restrict__ Wq,
    const float* __restrict__ Wk, const float* __restrict__ Wv,
    const float* __restrict__ Wo, ushort* __restrict__ Xb,
    ushort* __restrict__ Wqb, ushort* __restrict__ Wkb,
    ushort* __restrict__ Wvb, ushort* __restrict__ Wob) {
  int i = blockIdx.x * 256 + threadIdx.x;  // chunk index (8 elements)
  const float* src;
  ushort* dst;
  int j;
  if (i < 262144)      { src = X;  dst = Xb;  j = i; }
  else if (i < 393216) { src = Wq; dst = Wqb; j = i - 262144; }
  else if (i < 524288) { src = Wk; dst = Wkb; j = i - 393216; }
  else if (i < 655360) { src = Wv; dst = Wvb; j = i - 524288; }
  else                 { src = Wo; dst = Wob; j = i - 655360; }
  float4 a = *reinterpret_cast<const float4*>(src + j * 8);
  float4 b = *reinterpret_cast<const float4*>(src + j * 8 + 4);
  *reinterpret_cast<uint4*>(dst + j * 8) = rne8(a, b);
}

// ---------------------------------------------------------------------------
// cos/sin table
// ---------------------------------------------------------------------------
__global__ __launch_bounds__(64) void k_cs(float* __restrict__ cs) {
  int s = blockIdx.x * 2 + (threadIdx.x >> 5);
  int p = threadIdx.x & 31;
  float invf = powf(10000.0f, (-2.0f * p) / 64.0f);
  float sn, c;
  sincosf((float)s * invf, &sn, &c);
  cs[s * 64 + 2 * p] = c;
  cs[s * 64 + 2 * p + 1] = sn;
}

// ---------------------------------------------------------------------------
// A[h,t,i] = (1/8) * sum_j proj[h,j] * tpl_norm[h,t,(i-j) mod 64]  -> hi/lo bf16
// ---------------------------------------------------------------------------
__global__ __launch_bounds__(64) void k_prep_A(const float* __restrict__ tpl,
                                               const float* __restrict__ proj,
                                               ushort* __restrict__ Ahh,
                                               ushort* __restrict__ Ahl) {
  int ht = blockIdx.x;
  int h = ht >> 5;
  int lane = threadIdx.x;
  float tv = tpl[ht * 64 + lane];
  float ss = tv * tv;
#pragma unroll
  for (int off = 1; off < 64; off <<= 1) ss += __shfl_xor(ss, off);
  float rn = 1.0f / fmaxf(sqrtf(ss), 1e-12f);
  __shared__ float tn[64];
  tn[lane] = tv * rn;
  __syncthreads();
  float acc = 0.f;
#pragma unroll
  for (int j = 0; j < 64; ++j) acc += proj[h * 64 + j] * tn[(lane - j) & 63];
  float v = acc * 0.125f;
  uint u = __builtin_bit_cast(uint, v);
  uint hi = u >> 16;
  float fh = __builtin_bit_cast(float, u & 0xffff0000u);
  uint lo = __builtin_bit_cast(uint, v - fh) >> 16;
  Ahh[ht * 64 + lane] = (ushort)hi;
  Ahl[ht * 64 + lane] = (ushort)lo;
}

// ---------------------------------------------------------------------------
// QKV GEMM: round-7 validated layout (tile 128x64, BK=32, 64B LDS rows,
// ((row>>1)&3) XOR swizzle) + 2-phase double-buffered pipeline:
//   issue next-tile global loads -> compute current buffer -> write other
//   buffer -> ONE barrier. Loads stay in flight across the compute phase.
// Epilogues (z<2 RoPE+signature, z==2 transposed-bf16 V) verbatim.
// ---------------------------------------------------------------------------
__global__ __launch_bounds__(256) void k_qkv(
    const ushort* __restrict__ Xb,
    const ushort* __restrict__ Wqb, const ushort* __restrict__ Wkb,
    const ushort* __restrict__ Wvb,
    const ushort* __restrict__ Ahh, const ushort* __restrict__ Ahl,
    const float* __restrict__ cs,
    ushort* __restrict__ Qs, ushort* __restrict__ Ks,
    ushort* __restrict__ Vt) {
  // buf0 @0 (A 8KB + B 4KB), buf1 @12288 | dmp f32 [128][68] aliases all
  __shared__ __align__(16) char smem[34816];

  const int z = blockIdx.z;
  const ushort* Wm = (z == 0) ? Wqb : (z == 1) ? Wkb : Wvb;
  const int m0 = blockIdx.y * 128;
  const int n0 = blockIdx.x * 64;
  const int h = blockIdx.x;

  const int tid = threadIdx.x;
  const int l = tid & 63;
  const int wid = tid >> 6;
  const int wr = wid >> 1, wc = wid & 1;
  const int l31 = l & 31, lhi = l >> 5;

  const int sr = tid >> 2;   // staging row 0..63
  const int sc = tid & 3;    // staging 16B col 0..3

  // precomputed swizzled LDS offsets (row-invariant across iterations)
  const int offA0 = (sr) * 64 + ((sc ^ ((sr >> 1) & 3)) << 4);
  const int offA1 = (sr + 64) * 64 + ((sc ^ (((sr + 64) >> 1) & 3)) << 4);
  const int offB = 8192 + sr * 64 + ((sc ^ ((sr >> 1) & 3)) << 4);

  const ushort* apsrc0 = Xb + (size_t)(m0 + sr) * 1024 + sc * 8;
  const ushort* apsrc1 = Xb + (size_t)(m0 + sr + 64) * 1024 + sc * 8;
  const ushort* bpsrc = Wm + (size_t)(n0 + sr) * 1024 + sc * 8;

  f32x16 acc0 = 0.0f, acc1 = 0.0f;

  // prologue: stage tile 0 into buf0
  {
    uint4 a0 = *reinterpret_cast<const uint4*>(apsrc0);
    uint4 a1 = *reinterpret_cast<const uint4*>(apsrc1);
    uint4 b = *reinterpret_cast<const uint4*>(bpsrc);
    *reinterpret_cast<uint4*>(smem + offA0) = a0;
    *reinterpret_cast<uint4*>(smem + offA1) = a1;
    *reinterpret_cast<uint4*>(smem + offB) = b;
  }
  __syncthreads();

  int cur = 0;
  for (int t = 0; t < 32; ++t) {
    const bool more = (t < 31);
    uint4 na0, na1, nb;
    if (more) {
      const int kn = (t + 1) * 32;
      na0 = *reinterpret_cast<const uint4*>(apsrc0 + kn);
      na1 = *reinterpret_cast<const uint4*>(apsrc1 + kn);
      nb = *reinterpret_cast<const uint4*>(bpsrc + kn);
    }

    const char* base = smem + cur * 12288;
#pragma unroll
    for (int kst = 0; kst < 2; ++kst) {
      FragU ah0, ah1, bh;
      {
        int row = wr * 64 + l31;
        int cc = (kst * 2 + lhi) ^ ((row >> 1) & 3);
        ah0.q = *reinterpret_cast<const uint4*>(base + row * 64 + cc * 16);
      }
      {
        int row = wr * 64 + 32 + l31;
        int cc = (kst * 2 + lhi) ^ ((row >> 1) & 3);
        ah1.q = *reinterpret_cast<const uint4*>(base + row * 64 + cc * 16);
      }
      {
        int brow = wc * 32 + l31;
        int bcc = (kst * 2 + lhi) ^ ((brow >> 1) & 3);
        bh.q = *reinterpret_cast<const uint4*>(base + 8192 + brow * 64 + bcc * 16);
      }
      acc0 = MFMA(ah0.v, bh.v, acc0);
      acc1 = MFMA(ah1.v, bh.v, acc1);
    }

    if (more) {
      char* dst = smem + (cur ^ 1) * 12288;
      *reinterpret_cast<uint4*>(dst + offA0) = na0;
      *reinterpret_cast<uint4*>(dst + offA1) = na1;
      *reinterpret_cast<uint4*>(dst + offB) = nb;
      __syncthreads();
      cur ^= 1;
    }
  }

  if (z == 2) {
    int d = wc * 32 + l31;
#pragma unroll
    for (int fm = 0; fm < 2; ++fm) {
      const f32x16& a = fm ? acc1 : acc0;
#pragma unroll
      for (int j = 0; j < 16; ++j) {
        int rl = fm * 32 + (j & 3) + ((j >> 2) & 3) * 8 + 4 * lhi;
        int m = m0 + wr * 64 + rl;
        int b = m >> 10, s = m & 1023;
        Vt[((size_t)((b * 16 + h) * 64 + d)) * 1024 + s] = (ushort)rne16(a[j]);
      }
    }
    return;
  }

  ushort* Sig = (z == 0) ? Qs : Ks;
  float* dmp = reinterpret_cast<float*>(smem);  // [128][68] f32
  __syncthreads();
#pragma unroll
  for (int fm = 0; fm < 2; ++fm) {
    const f32x16& a = fm ? acc1 : acc0;
#pragma unroll
    for (int j = 0; j < 16; ++j) {
      int rl = fm * 32 + (j & 3) + ((j >> 2) & 3) * 8 + 4 * lhi;
      dmp[(wr * 64 + rl) * 68 + wc * 32 + l31] = a[j];
    }
  }
  __syncthreads();

  int srow = wr * 64 + wc * 32 + l31;
  int sq = (m0 + srow) & 1023;
  f32x16 sacc = 0.0f;
#pragma unroll
  for (int kst = 0; kst < 4; ++kst) {
    const float* dp = &dmp[srow * 68 + kst * 16 + lhi * 8];
    float4 x0 = *reinterpret_cast<const float4*>(dp);
    float4 x1 = *reinterpret_cast<const float4*>(dp + 4);
    const float* cp = &cs[sq * 64 + kst * 16 + lhi * 8];
    float4 c0 = *reinterpret_cast<const float4*>(cp);
    float4 c1 = *reinterpret_cast<const float4*>(cp + 4);
    float r[8];
    r[0] = x0.x * c0.x - x0.y * c0.y;
    r[1] = x0.x * c0.y + x0.y * c0.x;
    r[2] = x0.z * c0.z - x0.w * c0.w;
    r[3] = x0.z * c0.w + x0.w * c0.z;
    r[4] = x1.x * c1.x - x1.y * c1.y;
    r[5] = x1.x * c1.y + x1.y * c1.x;
    r[6] = x1.z * c1.z - x1.w * c1.w;
    r[7] = x1.z * c1.w + x1.w * c1.z;
    FragU ah, al;
    split8a(r, ah.q, al.q);
    size_t boff = ((size_t)(h * 32 + l31) * 64 + kst * 16 + lhi * 8);
    FragU bh, bl;
    bh.q = *reinterpret_cast<const uint4*>(Ahh + boff);
    bl.q = *reinterpret_cast<const uint4*>(Ahl + boff);
    sacc = MFMA(al.v, bh.v, sacc);
    sacc = MFMA(ah.v, bl.v, sacc);
    sacc = MFMA(ah.v, bh.v, sacc);
  }
#pragma unroll
  for (int j = 0; j < 16; ++j) {
    float v = sacc[j];
    float ss = v * v;
    ss += __shfl_xor(ss, 1);
    ss += __shfl_xor(ss, 2);
    ss += __shfl_xor(ss, 4);
    ss += __shfl_xor(ss, 8);
    ss += __shfl_xor(ss, 16);
    float rn = 1.0f / fmaxf(sqrtf(ss), 1e-12f);
    int rl = (j & 3) + ((j >> 2) & 3) * 8 + 4 * lhi;
    int m = m0 + wr * 64 + wc * 32 + rl;
    int bb = m >> 10, s2 = m & 1023;
    Sig[(((size_t)(bb * 16 + h)) * 1024 + s2) * 32 + l31] =
        (ushort)rne16(v * rn);
  }
}

// ---------------------------------------------------------------------------
// MFMA attention (validated round-5/7, unchanged).
// ---------------------------------------------------------------------------
__global__ __launch_bounds__(128) void k_attn(const ushort* __restrict__ Qs,
                                              const ushort* __restrict__ Ks,
                                              const ushort* __restrict__ Vt,
                                              ushort* __restrict__ O) {
  __shared__ ushort plds[2][32][68];

  const int tid = threadIdx.x;
  const int l = tid & 63;
  const int wid = tid >> 6;
  const int l31 = l & 31, lhi = l >> 5;
  const int bh = blockIdx.y;
  const int q0 = blockIdx.x * 64 + wid * 32;

  FragU aq0, aq1;
  {
    const ushort* qp = Qs + ((size_t)bh * 1024 + q0 + l31) * 32 + lhi * 8;
    aq0.q = *reinterpret_cast<const uint4*>(qp);
    aq1.q = *reinterpret_cast<const uint4*>(qp + 16);
  }

  const ushort* kbase = Ks + (size_t)bh * 1024 * 32;
  const ushort* vbase = Vt + (size_t)bh * 64 * 1024;

  f32x16 oacc0 = 0.0f, oacc1 = 0.0f;
  float pden[16];
#pragma unroll
  for (int r = 0; r < 16; ++r) pden[r] = 0.f;

  for (int kt = 0; kt < 16; ++kt) {
    const int k0 = kt * 64;
    f32x16 sacc[2];
    sacc[0] = 0.0f;
    sacc[1] = 0.0f;
#pragma unroll
    for (int nt = 0; nt < 2; ++nt) {
      const ushort* kp = kbase + (size_t)(k0 + nt * 32 + l31) * 32 + lhi * 8;
      FragU b0, b1;
      b0.q = *reinterpret_cast<const uint4*>(kp);
      b1.q = *reinterpret_cast<const uint4*>(kp + 16);
      sacc[nt] = MFMA(aq0.v, b0.v, sacc[nt]);
      sacc[nt] = MFMA(aq1.v, b1.v, sacc[nt]);
    }
#pragma unroll
    for (int nt = 0; nt < 2; ++nt) {
#pragma unroll
      for (int r = 0; r < 16; ++r) {
        float e = __expf(sacc[nt][r] * SCALE_F);
        pden[r] += e;
        int q = (r & 3) + ((r >> 2) << 3) + 4 * lhi;
        plds[wid][q][nt * 32 + l31] = (ushort)rne16(e);
      }
    }
    __builtin_amdgcn_wave_barrier();
#pragma unroll
    for (int kst = 0; kst < 4; ++kst) {
      FragU ap;
      const ushort* pp = &plds[wid][l31][kst * 16 + lhi * 8];
      uint2 plo = *reinterpret_cast<const uint2*>(pp);
      uint2 phi = *reinterpret_cast<const uint2*>(pp + 4);
      ap.q = make_uint4(plo.x, plo.y, phi.x, phi.y);
      FragU bv0, bv1;
      const ushort* vp0 = vbase + (size_t)l31 * 1024 + k0 + kst * 16 + lhi * 8;
      bv0.q = *reinterpret_cast<const uint4*>(vp0);
      bv1.q = *reinterpret_cast<const uint4*>(vp0 + 32 * 1024);
      oacc0 = MFMA(ap.v, bv0.v, oacc0);
      oacc1 = MFMA(ap.v, bv1.v, oacc1);
    }
  }

#pragma unroll
  for (int r = 0; r < 16; ++r) {
    float s = pden[r];
    s += __shfl_xor(s, 1);
    s += __shfl_xor(s, 2);
    s += __shfl_xor(s, 4);
    s += __shfl_xor(s, 8);
    s += __shfl_xor(s, 16);
    pden[r] = 1.0f / s;
  }

  const int b = bh >> 4, h = bh & 15;
#pragma unroll
  for (int r = 0; r < 16; ++r) {
    int q = q0 + (r & 3) + ((r >> 2) << 3) + 4 * lhi;
    size_t row = ((size_t)b * 1024 + q) * 1024 + h * 64;
    O[row + l31] = (ushort)rne16(oacc0[r] * pden[r]);
    O[row + 32 + l31] = (ushort)rne16(oacc1[r] * pden[r]);
  }
}

// ---------------------------------------------------------------------------
// Final projection: 64x64 tile, all-bf16, 2-phase double-buffered pipeline.
// ---------------------------------------------------------------------------
__global__ __launch_bounds__(256) void k_final(const ushort* __restrict__ Xb,
                                               const ushort* __restrict__ Wb,
                                               float* __restrict__ Y) {
  // buf0 @0 (A 4KB + B 4KB), buf1 @8192
  __shared__ __align__(16) char smem[16384];

  const int m0 = blockIdx.y * 64;
  const int n0 = blockIdx.x * 64;
  const int tid = threadIdx.x;
  const int l = tid & 63;
  const int wid = tid >> 6;
  const int wr = wid >> 1, wc = wid & 1;
  const int l31 = l & 31, lhi = l >> 5;
  const int sr = tid >> 2;
  const int sc = tid & 3;

  const int offA = sr * 64 + ((sc ^ ((sr >> 1) & 3)) << 4);
  const int offB = 4096 + offA;
  const ushort* apsrc = Xb + (size_t)(m0 + sr) * 1024 + sc * 8;
  const ushort* bpsrc = Wb + (size_t)(n0 + sr) * 1024 + sc * 8;

  f32x16 acc = 0.0f;

  {
    uint4 av = *reinterpret_cast<const uint4*>(apsrc);
    uint4 bv = *reinterpret_cast<const uint4*>(bpsrc);
    *reinterpret_cast<uint4*>(smem + offA) = av;
    *reinterpret_cast<uint4*>(smem + offB) = bv;
  }
  __syncthreads();

  int cur = 0;
  for (int t = 0; t < 32; ++t) {
    const bool more = (t < 31);
    uint4 na, nb;
    if (more) {
      const int kn = (t + 1) * 32;
      na = *reinterpret_cast<const uint4*>(apsrc + kn);
      nb = *reinterpret_cast<const uint4*>(bpsrc + kn);
    }

    const char* base = smem + cur * 8192;
#pragma unroll
    for (int kst = 0; kst < 2; ++kst) {
      FragU ah, bh;
      int row = wr * 32 + l31;
      int cc = (kst * 2 + lhi) ^ ((row >> 1) & 3);
      ah.q = *reinterpret_cast<const uint4*>(base + row * 64 + cc * 16);
      int brow = wc * 32 + l31;
      int bcc = (kst * 2 + lhi) ^ ((brow >> 1) & 3);
      bh.q = *reinterpret_cast<const uint4*>(base + 4096 + brow * 64 + bcc * 16);
      acc = MFMA(ah.v, bh.v, acc);
    }

    if (more) {
      char* dst = smem + (cur ^ 1) * 8192;
      *reinterpret_cast<uint4*>(dst + offA) = na;
      *reinterpret_cast<uint4*>(dst + offB) = nb;
      __syncthreads();
      cur ^= 1;
    }
  }

#pragma unroll
  for (int j = 0; j < 16; ++j) {
    int rl = (j & 3) + ((j >> 2) & 3) * 8 + 4 * lhi;
    int m = m0 + wr * 32 + rl;
    Y[(size_t)m * 1024 + n0 + wc * 32 + l31] = acc[j];
  }
}

// ---------------------------------------------------------------------------
extern "C" void kernel_launch(void* const* d_in, const int* in_sizes, int n_in,
                              void* d_out, int out_size, void* d_ws,
                              size_t ws_size, hipStream_t stream) {
  const float* x = (const float*)d_in[0];
  const float* Wq = (const float*)d_in[1];
  const float* Wk = (const float*)d_in[2];
  const float* Wv = (const float*)d_in[3];
  const float* Wo = (const float*)d_in[4];
  const float* tpl = (const float*)d_in[5];
  const float* proj = (const float*)d_in[6];
  float* out = (float*)d_out;

  char* ws = (char*)d_ws;
  size_t off = 0;
  auto alloc = [&](size_t bytes) {
    void* p = ws + off;
    off += (bytes + 255) & ~(size_t)255;
    return p;
  };

  const size_t MB = 1024 * 1024;
  bool big = ws_size >= 22 * MB;

  ushort *Xb, *Wvb, *obuf;
  float* cs;
  ushort *Ahh, *Ahl, *Wqb, *Wkb, *Wob, *qs, *ks, *vt;

  if (big) {
    Xb = (ushort*)alloc(4 * MB);
    cs = (float*)alloc((size_t)1024 * 64 * 4);
    Ahh = (ushort*)alloc((size_t)16 * 32 * 64 * 2);
    Ahl = (ushort*)alloc((size_t)16 * 32 * 64 * 2);
    Wqb = (ushort*)alloc(2 * MB);
    Wkb = (ushort*)alloc(2 * MB);
    Wvb = (ushort*)alloc(2 * MB);
    Wob = (ushort*)alloc(2 * MB);
    qs = (ushort*)alloc(2 * MB);
    ks = (ushort*)alloc(2 * MB);
    vt = (ushort*)alloc(4 * MB);
    obuf = Xb;  // Xb dead after k_qkv
  } else {
    cs = (float*)alloc((size_t)1024 * 64 * 4);
    Ahh = (ushort*)alloc((size_t)16 * 32 * 64 * 2);
    Ahl = (ushort*)alloc((size_t)16 * 32 * 64 * 2);
    Wqb = (ushort*)alloc(2 * MB);
    Wkb = (ushort*)alloc(2 * MB);
    Wob = (ushort*)alloc(2 * MB);
    qs = (ushort*)alloc(2 * MB);
    ks = (ushort*)alloc(2 * MB);
    vt = (ushort*)alloc(4 * MB);
    obuf = (ushort*)ws;  // aliases [cs..Wkb] (dead after k_qkv)
    Xb = (ushort*)d_out;
    Wvb = (ushort*)((char*)d_out + 4 * MB);
  }

  k_cvtall<<<dim3(3072), dim3(256), 0, stream>>>(x, Wq, Wk, Wv, Wo, Xb, Wqb,
                                                 Wkb, Wvb, Wob);
  k_cs<<<dim3(512), dim3(64), 0, stream>>>(cs);
  k_prep_A<<<dim3(512), dim3(64), 0, stream>>>(tpl, proj, Ahh, Ahl);
  k_qkv<<<dim3(16, 16, 3), dim3(256), 0, stream>>>(Xb, Wqb, Wkb, Wvb, Ahh, Ahl,
                                                   cs, qs, ks, vt);
  k_attn<<<dim3(16, 32), dim3(128), 0, stream>>>(qs, ks, vt, obuf);
  k_final<<<dim3(16, 32), dim3(256), 0, stream>>>(obuf, Wob, out);
}

// Round 9
// 95.472 us; speedup vs baseline: 1.6521x; 1.0544x over previous
//
#include <hip/hip_runtime.h>
#include <math.h>

#define S_ 1024
#define T_ 32
#define SCALE_F 0.7071067811865476f

typedef unsigned int uint;
typedef unsigned short ushort;
typedef __bf16 bf16x8 __attribute__((ext_vector_type(8)));
typedef float f32x16 __attribute__((ext_vector_type(16)));

union FragU { uint4 q; bf16x8 v; };

#define MFMA(a, b, c) __builtin_amdgcn_mfma_f32_32x32x16_bf16((a), (b), (c), 0, 0, 0)

__device__ __forceinline__ uint rne16(float f) {
  uint u = __builtin_bit_cast(uint, f);
  u += 0x7fffu + ((u >> 16) & 1u);
  return u >> 16;
}

__device__ __forceinline__ void split8a(const float* f, uint4& hi, uint4& lo) {
  uint h[8], m[8];
#pragma unroll
  for (int i = 0; i < 8; ++i) {
    uint u = __builtin_bit_cast(uint, f[i]);
    h[i] = u >> 16;
    float fh = __builtin_bit_cast(float, u & 0xffff0000u);
    m[i] = __builtin_bit_cast(uint, f[i] - fh) >> 16;
  }
  hi = make_uint4(h[0] | (h[1] << 16), h[2] | (h[3] << 16),
                  h[4] | (h[5] << 16), h[6] | (h[7] << 16));
  lo = make_uint4(m[0] | (m[1] << 16), m[2] | (m[3] << 16),
                  m[4] | (m[5] << 16), m[6] | (m[7] << 16));
}

__device__ __forceinline__ uint4 rne8(const float4& A, const float4& B) {
  float f[8] = {A.x, A.y, A.z, A.w, B.x, B.y, B.z, B.w};
  uint h[8];
#pragma unroll
  for (int i = 0; i < 8; ++i) h[i] = rne16(f[i]);
  return make_uint4(h[0] | (h[1] << 16), h[2] | (h[3] << 16),
                    h[4] | (h[5] << 16), h[6] | (h[7] << 16));
}

// ---------------------------------------------------------------------------
// Bulk f32->bf16: X (2M el), Wq, Wk, Wv, Wo (1M each). 8 el/thread.
// ---------------------------------------------------------------------------
__global__ __launch_bounds__(256) void k_cvtall(
    const float* __restrict__ X, const float* __restrict__ Wq,
    const float* __restrict__ Wk, const float* __restrict__ Wv,
    const float* __restrict__ Wo, ushort* __restrict__ Xb,
    ushort* __restrict__ Wqb, ushort* __restrict__ Wkb,
    ushort* __restrict__ Wvb, ushort* __restrict__ Wob) {
  int i = blockIdx.x * 256 + threadIdx.x;  // chunk index (8 elements)
  const float* src;
  ushort* dst;
  int j;
  if (i < 262144)      { src = X;  dst = Xb;  j = i; }
  else if (i < 393216) { src = Wq; dst = Wqb; j = i - 262144; }
  else if (i < 524288) { src = Wk; dst = Wkb; j = i - 393216; }
  else if (i < 655360) { src = Wv; dst = Wvb; j = i - 524288; }
  else                 { src = Wo; dst = Wob; j = i - 655360; }
  float4 a = *reinterpret_cast<const float4*>(src + j * 8);
  float4 b = *reinterpret_cast<const float4*>(src + j * 8 + 4);
  *reinterpret_cast<uint4*>(dst + j * 8) = rne8(a, b);
}

// ---------------------------------------------------------------------------
// cos/sin table
// ---------------------------------------------------------------------------
__global__ __launch_bounds__(64) void k_cs(float* __restrict__ cs) {
  int s = blockIdx.x * 2 + (threadIdx.x >> 5);
  int p = threadIdx.x & 31;
  float invf = powf(10000.0f, (-2.0f * p) / 64.0f);
  float sn, c;
  sincosf((float)s * invf, &sn, &c);
  cs[s * 64 + 2 * p] = c;
  cs[s * 64 + 2 * p + 1] = sn;
}

// ---------------------------------------------------------------------------
// A[h,t,i] = (1/8) * sum_j proj[h,j] * tpl_norm[h,t,(i-j) mod 64]  -> hi/lo bf16
// ---------------------------------------------------------------------------
__global__ __launch_bounds__(64) void k_prep_A(const float* __restrict__ tpl,
                                               const float* __restrict__ proj,
                                               ushort* __restrict__ Ahh,
                                               ushort* __restrict__ Ahl) {
  int ht = blockIdx.x;
  int h = ht >> 5;
  int lane = threadIdx.x;
  float tv = tpl[ht * 64 + lane];
  float ss = tv * tv;
#pragma unroll
  for (int off = 1; off < 64; off <<= 1) ss += __shfl_xor(ss, off);
  float rn = 1.0f / fmaxf(sqrtf(ss), 1e-12f);
  __shared__ float tn[64];
  tn[lane] = tv * rn;
  __syncthreads();
  float acc = 0.f;
#pragma unroll
  for (int j = 0; j < 64; ++j) acc += proj[h * 64 + j] * tn[(lane - j) & 63];
  float v = acc * 0.125f;
  uint u = __builtin_bit_cast(uint, v);
  uint hi = u >> 16;
  float fh = __builtin_bit_cast(float, u & 0xffff0000u);
  uint lo = __builtin_bit_cast(uint, v - fh) >> 16;
  Ahh[ht * 64 + lane] = (ushort)hi;
  Ahl[ht * 64 + lane] = (ushort)lo;
}

// ---------------------------------------------------------------------------
// QKV GEMM (validated round-8): 2-phase double-buffered pipeline.
// ---------------------------------------------------------------------------
__global__ __launch_bounds__(256) void k_qkv(
    const ushort* __restrict__ Xb,
    const ushort* __restrict__ Wqb, const ushort* __restrict__ Wkb,
    const ushort* __restrict__ Wvb,
    const ushort* __restrict__ Ahh, const ushort* __restrict__ Ahl,
    const float* __restrict__ cs,
    ushort* __restrict__ Qs, ushort* __restrict__ Ks,
    ushort* __restrict__ Vt) {
  __shared__ __align__(16) char smem[34816];

  const int z = blockIdx.z;
  const ushort* Wm = (z == 0) ? Wqb : (z == 1) ? Wkb : Wvb;
  const int m0 = blockIdx.y * 128;
  const int n0 = blockIdx.x * 64;
  const int h = blockIdx.x;

  const int tid = threadIdx.x;
  const int l = tid & 63;
  const int wid = tid >> 6;
  const int wr = wid >> 1, wc = wid & 1;
  const int l31 = l & 31, lhi = l >> 5;

  const int sr = tid >> 2;
  const int sc = tid & 3;

  const int offA0 = (sr) * 64 + ((sc ^ ((sr >> 1) & 3)) << 4);
  const int offA1 = (sr + 64) * 64 + ((sc ^ (((sr + 64) >> 1) & 3)) << 4);
  const int offB = 8192 + sr * 64 + ((sc ^ ((sr >> 1) & 3)) << 4);

  const ushort* apsrc0 = Xb + (size_t)(m0 + sr) * 1024 + sc * 8;
  const ushort* apsrc1 = Xb + (size_t)(m0 + sr + 64) * 1024 + sc * 8;
  const ushort* bpsrc = Wm + (size_t)(n0 + sr) * 1024 + sc * 8;

  f32x16 acc0 = 0.0f, acc1 = 0.0f;

  {
    uint4 a0 = *reinterpret_cast<const uint4*>(apsrc0);
    uint4 a1 = *reinterpret_cast<const uint4*>(apsrc1);
    uint4 b = *reinterpret_cast<const uint4*>(bpsrc);
    *reinterpret_cast<uint4*>(smem + offA0) = a0;
    *reinterpret_cast<uint4*>(smem + offA1) = a1;
    *reinterpret_cast<uint4*>(smem + offB) = b;
  }
  __syncthreads();

  int cur = 0;
  for (int t = 0; t < 32; ++t) {
    const bool more = (t < 31);
    uint4 na0, na1, nb;
    if (more) {
      const int kn = (t + 1) * 32;
      na0 = *reinterpret_cast<const uint4*>(apsrc0 + kn);
      na1 = *reinterpret_cast<const uint4*>(apsrc1 + kn);
      nb = *reinterpret_cast<const uint4*>(bpsrc + kn);
    }

    const char* base = smem + cur * 12288;
#pragma unroll
    for (int kst = 0; kst < 2; ++kst) {
      FragU ah0, ah1, bh;
      {
        int row = wr * 64 + l31;
        int cc = (kst * 2 + lhi) ^ ((row >> 1) & 3);
        ah0.q = *reinterpret_cast<const uint4*>(base + row * 64 + cc * 16);
      }
      {
        int row = wr * 64 + 32 + l31;
        int cc = (kst * 2 + lhi) ^ ((row >> 1) & 3);
        ah1.q = *reinterpret_cast<const uint4*>(base + row * 64 + cc * 16);
      }
      {
        int brow = wc * 32 + l31;
        int bcc = (kst * 2 + lhi) ^ ((brow >> 1) & 3);
        bh.q = *reinterpret_cast<const uint4*>(base + 8192 + brow * 64 + bcc * 16);
      }
      acc0 = MFMA(ah0.v, bh.v, acc0);
      acc1 = MFMA(ah1.v, bh.v, acc1);
    }

    if (more) {
      char* dst = smem + (cur ^ 1) * 12288;
      *reinterpret_cast<uint4*>(dst + offA0) = na0;
      *reinterpret_cast<uint4*>(dst + offA1) = na1;
      *reinterpret_cast<uint4*>(dst + offB) = nb;
      __syncthreads();
      cur ^= 1;
    }
  }

  if (z == 2) {
    int d = wc * 32 + l31;
#pragma unroll
    for (int fm = 0; fm < 2; ++fm) {
      const f32x16& a = fm ? acc1 : acc0;
#pragma unroll
      for (int j = 0; j < 16; ++j) {
        int rl = fm * 32 + (j & 3) + ((j >> 2) & 3) * 8 + 4 * lhi;
        int m = m0 + wr * 64 + rl;
        int b = m >> 10, s = m & 1023;
        Vt[((size_t)((b * 16 + h) * 64 + d)) * 1024 + s] = (ushort)rne16(a[j]);
      }
    }
    return;
  }

  ushort* Sig = (z == 0) ? Qs : Ks;
  float* dmp = reinterpret_cast<float*>(smem);  // [128][68] f32
  __syncthreads();
#pragma unroll
  for (int fm = 0; fm < 2; ++fm) {
    const f32x16& a = fm ? acc1 : acc0;
#pragma unroll
    for (int j = 0; j < 16; ++j) {
      int rl = fm * 32 + (j & 3) + ((j >> 2) & 3) * 8 + 4 * lhi;
      dmp[(wr * 64 + rl) * 68 + wc * 32 + l31] = a[j];
    }
  }
  __syncthreads();

  int srow = wr * 64 + wc * 32 + l31;
  int sq = (m0 + srow) & 1023;
  f32x16 sacc = 0.0f;
#pragma unroll
  for (int kst = 0; kst < 4; ++kst) {
    const float* dp = &dmp[srow * 68 + kst * 16 + lhi * 8];
    float4 x0 = *reinterpret_cast<const float4*>(dp);
    float4 x1 = *reinterpret_cast<const float4*>(dp + 4);
    const float* cp = &cs[sq * 64 + kst * 16 + lhi * 8];
    float4 c0 = *reinterpret_cast<const float4*>(cp);
    float4 c1 = *reinterpret_cast<const float4*>(cp + 4);
    float r[8];
    r[0] = x0.x * c0.x - x0.y * c0.y;
    r[1] = x0.x * c0.y + x0.y * c0.x;
    r[2] = x0.z * c0.z - x0.w * c0.w;
    r[3] = x0.z * c0.w + x0.w * c0.z;
    r[4] = x1.x * c1.x - x1.y * c1.y;
    r[5] = x1.x * c1.y + x1.y * c1.x;
    r[6] = x1.z * c1.z - x1.w * c1.w;
    r[7] = x1.z * c1.w + x1.w * c1.z;
    FragU ah, al;
    split8a(r, ah.q, al.q);
    size_t boff = ((size_t)(h * 32 + l31) * 64 + kst * 16 + lhi * 8);
    FragU bh, bl;
    bh.q = *reinterpret_cast<const uint4*>(Ahh + boff);
    bl.q = *reinterpret_cast<const uint4*>(Ahl + boff);
    sacc = MFMA(al.v, bh.v, sacc);
    sacc = MFMA(ah.v, bl.v, sacc);
    sacc = MFMA(ah.v, bh.v, sacc);
  }
#pragma unroll
  for (int j = 0; j < 16; ++j) {
    float v = sacc[j];
    float ss = v * v;
    ss += __shfl_xor(ss, 1);
    ss += __shfl_xor(ss, 2);
    ss += __shfl_xor(ss, 4);
    ss += __shfl_xor(ss, 8);
    ss += __shfl_xor(ss, 16);
    float rn = 1.0f / fmaxf(sqrtf(ss), 1e-12f);
    int rl = (j & 3) + ((j >> 2) & 3) * 8 + 4 * lhi;
    int m = m0 + wr * 64 + wc * 32 + rl;
    int bb = m >> 10, s2 = m & 1023;
    Sig[(((size_t)(bb * 16 + h)) * 1024 + s2) * 32 + l31] =
        (ushort)rne16(v * rn);
  }
}

// ---------------------------------------------------------------------------
// Split-K MFMA attention. Grid (16, 32, 4): z = 256-key chunk. Additive
// online state (scores bounded -> no max-sub): partials merge by plain sum.
// Writes f32 partials Po[z][bh][q][64], Pd[z][bh][q]; k_attnred merges.
// ---------------------------------------------------------------------------
__global__ __launch_bounds__(128) void k_attn(const ushort* __restrict__ Qs,
                                              const ushort* __restrict__ Ks,
                                              const ushort* __restrict__ Vt,
                                              float* __restrict__ Po,
                                              float* __restrict__ Pd) {
  __shared__ ushort plds[2][32][68];

  const int tid = threadIdx.x;
  const int l = tid & 63;
  const int wid = tid >> 6;
  const int l31 = l & 31, lhi = l >> 5;
  const int bh = blockIdx.y;
  const int z = blockIdx.z;
  const int q0 = blockIdx.x * 64 + wid * 32;

  FragU aq0, aq1;
  {
    const ushort* qp = Qs + ((size_t)bh * 1024 + q0 + l31) * 32 + lhi * 8;
    aq0.q = *reinterpret_cast<const uint4*>(qp);
    aq1.q = *reinterpret_cast<const uint4*>(qp + 16);
  }

  const ushort* kbase = Ks + (size_t)bh * 1024 * 32;
  const ushort* vbase = Vt + (size_t)bh * 64 * 1024;

  f32x16 oacc0 = 0.0f, oacc1 = 0.0f;
  float pden[16];
#pragma unroll
  for (int r = 0; r < 16; ++r) pden[r] = 0.f;

  for (int kt = z * 4; kt < z * 4 + 4; ++kt) {
    const int k0 = kt * 64;
    f32x16 sacc[2];
    sacc[0] = 0.0f;
    sacc[1] = 0.0f;
#pragma unroll
    for (int nt = 0; nt < 2; ++nt) {
      const ushort* kp = kbase + (size_t)(k0 + nt * 32 + l31) * 32 + lhi * 8;
      FragU b0, b1;
      b0.q = *reinterpret_cast<const uint4*>(kp);
      b1.q = *reinterpret_cast<const uint4*>(kp + 16);
      sacc[nt] = MFMA(aq0.v, b0.v, sacc[nt]);
      sacc[nt] = MFMA(aq1.v, b1.v, sacc[nt]);
    }
#pragma unroll
    for (int nt = 0; nt < 2; ++nt) {
#pragma unroll
      for (int r = 0; r < 16; ++r) {
        float e = __expf(sacc[nt][r] * SCALE_F);
        pden[r] += e;
        int q = (r & 3) + ((r >> 2) << 3) + 4 * lhi;
        plds[wid][q][nt * 32 + l31] = (ushort)rne16(e);
      }
    }
    __builtin_amdgcn_wave_barrier();
#pragma unroll
    for (int kst = 0; kst < 4; ++kst) {
      FragU ap;
      const ushort* pp = &plds[wid][l31][kst * 16 + lhi * 8];
      uint2 plo = *reinterpret_cast<const uint2*>(pp);
      uint2 phi = *reinterpret_cast<const uint2*>(pp + 4);
      ap.q = make_uint4(plo.x, plo.y, phi.x, phi.y);
      FragU bv0, bv1;
      const ushort* vp0 = vbase + (size_t)l31 * 1024 + k0 + kst * 16 + lhi * 8;
      bv0.q = *reinterpret_cast<const uint4*>(vp0);
      bv1.q = *reinterpret_cast<const uint4*>(vp0 + 32 * 1024);
      oacc0 = MFMA(ap.v, bv0.v, oacc0);
      oacc1 = MFMA(ap.v, bv1.v, oacc1);
    }
  }

  // lane-reduce den partials (within 32-lane halves; q-rows match reg layout)
#pragma unroll
  for (int r = 0; r < 16; ++r) {
    float s = pden[r];
    s += __shfl_xor(s, 1);
    s += __shfl_xor(s, 2);
    s += __shfl_xor(s, 4);
    s += __shfl_xor(s, 8);
    s += __shfl_xor(s, 16);
    pden[r] = s;
  }

  const size_t zb = (size_t)z * 32 + bh;
#pragma unroll
  for (int r = 0; r < 16; ++r) {
    int q = q0 + (r & 3) + ((r >> 2) << 3) + 4 * lhi;
    size_t row = zb * 1024 + q;
    Po[row * 64 + l31] = oacc0[r];
    Po[row * 64 + 32 + l31] = oacc1[r];
    if (l31 == 0) Pd[row] = pden[r];
  }
}

// ---------------------------------------------------------------------------
// Merge 4 split-K partials: O = (sum_z Po) / (sum_z Pd), write bf16 obuf.
// Block = 4 waves, each wave one (bh,q) row (64 d lanes).
// ---------------------------------------------------------------------------
__global__ __launch_bounds__(256) void k_attnred(const float* __restrict__ Po,
                                                 const float* __restrict__ Pd,
                                                 ushort* __restrict__ O) {
  int idx = blockIdx.x * 4 + (threadIdx.x >> 6);  // row id: bh*1024 + q
  int d = threadIdx.x & 63;
  float den = 0.f, val = 0.f;
#pragma unroll
  for (int zc = 0; zc < 4; ++zc) {
    size_t row = (size_t)zc * 32768 + idx;
    den += Pd[row];
    val += Po[row * 64 + d];
  }
  int bh = idx >> 10, q = idx & 1023;
  int b = bh >> 4, h = bh & 15;
  O[((size_t)(b * 1024 + q)) * 1024 + h * 64 + d] = (ushort)rne16(val / den);
}

// ---------------------------------------------------------------------------
// Single-pass attention (round-8 validated) — fallback for small ws.
// ---------------------------------------------------------------------------
__global__ __launch_bounds__(128) void k_attn_mono(const ushort* __restrict__ Qs,
                                                   const ushort* __restrict__ Ks,
                                                   const ushort* __restrict__ Vt,
                                                   ushort* __restrict__ O) {
  __shared__ ushort plds[2][32][68];

  const int tid = threadIdx.x;
  const int l = tid & 63;
  const int wid = tid >> 6;
  const int l31 = l & 31, lhi = l >> 5;
  const int bh = blockIdx.y;
  const int q0 = blockIdx.x * 64 + wid * 32;

  FragU aq0, aq1;
  {
    const ushort* qp = Qs + ((size_t)bh * 1024 + q0 + l31) * 32 + lhi * 8;
    aq0.q = *reinterpret_cast<const uint4*>(qp);
    aq1.q = *reinterpret_cast<const uint4*>(qp + 16);
  }

  const ushort* kbase = Ks + (size_t)bh * 1024 * 32;
  const ushort* vbase = Vt + (size_t)bh * 64 * 1024;

  f32x16 oacc0 = 0.0f, oacc1 = 0.0f;
  float pden[16];
#pragma unroll
  for (int r = 0; r < 16; ++r) pden[r] = 0.f;

  for (int kt = 0; kt < 16; ++kt) {
    const int k0 = kt * 64;
    f32x16 sacc[2];
    sacc[0] = 0.0f;
    sacc[1] = 0.0f;
#pragma unroll
    for (int nt = 0; nt < 2; ++nt) {
      const ushort* kp = kbase + (size_t)(k0 + nt * 32 + l31) * 32 + lhi * 8;
      FragU b0, b1;
      b0.q = *reinterpret_cast<const uint4*>(kp);
      b1.q = *reinterpret_cast<const uint4*>(kp + 16);
      sacc[nt] = MFMA(aq0.v, b0.v, sacc[nt]);
      sacc[nt] = MFMA(aq1.v, b1.v, sacc[nt]);
    }
#pragma unroll
    for (int nt = 0; nt < 2; ++nt) {
#pragma unroll
      for (int r = 0; r < 16; ++r) {
        float e = __expf(sacc[nt][r] * SCALE_F);
        pden[r] += e;
        int q = (r & 3) + ((r >> 2) << 3) + 4 * lhi;
        plds[wid][q][nt * 32 + l31] = (ushort)rne16(e);
      }
    }
    __builtin_amdgcn_wave_barrier();
#pragma unroll
    for (int kst = 0; kst < 4; ++kst) {
      FragU ap;
      const ushort* pp = &plds[wid][l31][kst * 16 + lhi * 8];
      uint2 plo = *reinterpret_cast<const uint2*>(pp);
      uint2 phi = *reinterpret_cast<const uint2*>(pp + 4);
      ap.q = make_uint4(plo.x, plo.y, phi.x, phi.y);
      FragU bv0, bv1;
      const ushort* vp0 = vbase + (size_t)l31 * 1024 + k0 + kst * 16 + lhi * 8;
      bv0.q = *reinterpret_cast<const uint4*>(vp0);
      bv1.q = *reinterpret_cast<const uint4*>(vp0 + 32 * 1024);
      oacc0 = MFMA(ap.v, bv0.v, oacc0);
      oacc1 = MFMA(ap.v, bv1.v, oacc1);
    }
  }

#pragma unroll
  for (int r = 0; r < 16; ++r) {
    float s = pden[r];
    s += __shfl_xor(s, 1);
    s += __shfl_xor(s, 2);
    s += __shfl_xor(s, 4);
    s += __shfl_xor(s, 8);
    s += __shfl_xor(s, 16);
    pden[r] = 1.0f / s;
  }

  const int b = bh >> 4, h = bh & 15;
#pragma unroll
  for (int r = 0; r < 16; ++r) {
    int q = q0 + (r & 3) + ((r >> 2) << 3) + 4 * lhi;
    size_t row = ((size_t)b * 1024 + q) * 1024 + h * 64;
    O[row + l31] = (ushort)rne16(oacc0[r] * pden[r]);
    O[row + 32 + l31] = (ushort)rne16(oacc1[r] * pden[r]);
  }
}

// ---------------------------------------------------------------------------
// Final projection (validated round-8): 2-phase double-buffered pipeline.
// ---------------------------------------------------------------------------
__global__ __launch_bounds__(256) void k_final(const ushort* __restrict__ Xb,
                                               const ushort* __restrict__ Wb,
                                               float* __restrict__ Y) {
  __shared__ __align__(16) char smem[16384];

  const int m0 = blockIdx.y * 64;
  const int n0 = blockIdx.x * 64;
  const int tid = threadIdx.x;
  const int l = tid & 63;
  const int wid = tid >> 6;
  const int wr = wid >> 1, wc = wid & 1;
  const int l31 = l & 31, lhi = l >> 5;
  const int sr = tid >> 2;
  const int sc = tid & 3;

  const int offA = sr * 64 + ((sc ^ ((sr >> 1) & 3)) << 4);
  const int offB = 4096 + offA;
  const ushort* apsrc = Xb + (size_t)(m0 + sr) * 1024 + sc * 8;
  const ushort* bpsrc = Wb + (size_t)(n0 + sr) * 1024 + sc * 8;

  f32x16 acc = 0.0f;

  {
    uint4 av = *reinterpret_cast<const uint4*>(apsrc);
    uint4 bv = *reinterpret_cast<const uint4*>(bpsrc);
    *reinterpret_cast<uint4*>(smem + offA) = av;
    *reinterpret_cast<uint4*>(smem + offB) = bv;
  }
  __syncthreads();

  int cur = 0;
  for (int t = 0; t < 32; ++t) {
    const bool more = (t < 31);
    uint4 na, nb;
    if (more) {
      const int kn = (t + 1) * 32;
      na = *reinterpret_cast<const uint4*>(apsrc + kn);
      nb = *reinterpret_cast<const uint4*>(bpsrc + kn);
    }

    const char* base = smem + cur * 8192;
#pragma unroll
    for (int kst = 0; kst < 2; ++kst) {
      FragU ah, bh;
      int row = wr * 32 + l31;
      int cc = (kst * 2 + lhi) ^ ((row >> 1) & 3);
      ah.q = *reinterpret_cast<const uint4*>(base + row * 64 + cc * 16);
      int brow = wc * 32 + l31;
      int bcc = (kst * 2 + lhi) ^ ((brow >> 1) & 3);
      bh.q = *reinterpret_cast<const uint4*>(base + 4096 + brow * 64 + bcc * 16);
      acc = MFMA(ah.v, bh.v, acc);
    }

    if (more) {
      char* dst = smem + (cur ^ 1) * 8192;
      *reinterpret_cast<uint4*>(dst + offA) = na;
      *reinterpret_cast<uint4*>(dst + offB) = nb;
      __syncthreads();
      cur ^= 1;
    }
  }

#pragma unroll
  for (int j = 0; j < 16; ++j) {
    int rl = (j & 3) + ((j >> 2) & 3) * 8 + 4 * lhi;
    int m = m0 + wr * 32 + rl;
    Y[(size_t)m * 1024 + n0 + wc * 32 + l31] = acc[j];
  }
}

// ---------------------------------------------------------------------------
extern "C" void kernel_launch(void* const* d_in, const int* in_sizes, int n_in,
                              void* d_out, int out_size, void* d_ws,
                              size_t ws_size, hipStream_t stream) {
  const float* x = (const float*)d_in[0];
  const float* Wq = (const float*)d_in[1];
  const float* Wk = (const float*)d_in[2];
  const float* Wv = (const float*)d_in[3];
  const float* Wo = (const float*)d_in[4];
  const float* tpl = (const float*)d_in[5];
  const float* proj = (const float*)d_in[6];
  float* out = (float*)d_out;

  char* ws = (char*)d_ws;
  size_t off = 0;
  auto alloc = [&](size_t bytes) {
    void* p = ws + off;
    off += (bytes + 255) & ~(size_t)255;
    return p;
  };

  const size_t MB = 1024 * 1024;
  bool huge = ws_size >= 64 * MB;   // evidence (256MB ws poison): active path
  bool big = ws_size >= 22 * MB;

  ushort *Xb, *Wvb, *obuf;
  float* cs;
  ushort *Ahh, *Ahl, *Wqb, *Wkb, *Wob, *qs, *ks, *vt;
  float *Po = nullptr, *Pd = nullptr;

  if (big || huge) {
    Xb = (ushort*)alloc(4 * MB);
    cs = (float*)alloc((size_t)1024 * 64 * 4);
    Ahh = (ushort*)alloc((size_t)16 * 32 * 64 * 2);
    Ahl = (ushort*)alloc((size_t)16 * 32 * 64 * 2);
    Wqb = (ushort*)alloc(2 * MB);
    Wkb = (ushort*)alloc(2 * MB);
    Wvb = (ushort*)alloc(2 * MB);
    Wob = (ushort*)alloc(2 * MB);
    qs = (ushort*)alloc(2 * MB);
    ks = (ushort*)alloc(2 * MB);
    vt = (ushort*)alloc(4 * MB);
    if (huge) {
      Po = (float*)alloc(32 * MB);
      Pd = (float*)alloc((size_t)4 * 32768 * 4);
    }
    obuf = Xb;  // Xb dead after k_qkv
  } else {
    cs = (float*)alloc((size_t)1024 * 64 * 4);
    Ahh = (ushort*)alloc((size_t)16 * 32 * 64 * 2);
    Ahl = (ushort*)alloc((size_t)16 * 32 * 64 * 2);
    Wqb = (ushort*)alloc(2 * MB);
    Wkb = (ushort*)alloc(2 * MB);
    Wob = (ushort*)alloc(2 * MB);
    qs = (ushort*)alloc(2 * MB);
    ks = (ushort*)alloc(2 * MB);
    vt = (ushort*)alloc(4 * MB);
    obuf = (ushort*)ws;
    Xb = (ushort*)d_out;
    Wvb = (ushort*)((char*)d_out + 4 * MB);
  }

  k_cvtall<<<dim3(3072), dim3(256), 0, stream>>>(x, Wq, Wk, Wv, Wo, Xb, Wqb,
                                                 Wkb, Wvb, Wob);
  k_cs<<<dim3(512), dim3(64), 0, stream>>>(cs);
  k_prep_A<<<dim3(512), dim3(64), 0, stream>>>(tpl, proj, Ahh, Ahl);
  k_qkv<<<dim3(16, 16, 3), dim3(256), 0, stream>>>(Xb, Wqb, Wkb, Wvb, Ahh, Ahl,
                                                   cs, qs, ks, vt);
  if (huge) {
    k_attn<<<dim3(16, 32, 4), dim3(128), 0, stream>>>(qs, ks, vt, Po, Pd);
    k_attnred<<<dim3(8192), dim3(256), 0, stream>>>(Po, Pd, obuf);
  } else {
    k_attn_mono<<<dim3(16, 32), dim3(128), 0, stream>>>(qs, ks, vt, obuf);
  }
  k_final<<<dim3(16, 32), dim3(256), 0, stream>>>(obuf, Wob, out);
}

// Round 10
// 90.706 us; speedup vs baseline: 1.7389x; 1.0525x over previous
//
#include <hip/hip_runtime.h>
#include <math.h>

#define S_ 1024
#define T_ 32
#define SCALE_F 0.7071067811865476f

typedef unsigned int uint;
typedef unsigned short ushort;
typedef __bf16 bf16x8 __attribute__((ext_vector_type(8)));
typedef float f32x16 __attribute__((ext_vector_type(16)));

union FragU { uint4 q; bf16x8 v; };

#define MFMA(a, b, c) __builtin_amdgcn_mfma_f32_32x32x16_bf16((a), (b), (c), 0, 0, 0)

__device__ __forceinline__ uint rne16(float f) {
  uint u = __builtin_bit_cast(uint, f);
  u += 0x7fffu + ((u >> 16) & 1u);
  return u >> 16;
}

__device__ __forceinline__ float bf2f(ushort u) {
  return __builtin_bit_cast(float, ((uint)u) << 16);
}

__device__ __forceinline__ void split8a(const float* f, uint4& hi, uint4& lo) {
  uint h[8], m[8];
#pragma unroll
  for (int i = 0; i < 8; ++i) {
    uint u = __builtin_bit_cast(uint, f[i]);
    h[i] = u >> 16;
    float fh = __builtin_bit_cast(float, u & 0xffff0000u);
    m[i] = __builtin_bit_cast(uint, f[i] - fh) >> 16;
  }
  hi = make_uint4(h[0] | (h[1] << 16), h[2] | (h[3] << 16),
                  h[4] | (h[5] << 16), h[6] | (h[7] << 16));
  lo = make_uint4(m[0] | (m[1] << 16), m[2] | (m[3] << 16),
                  m[4] | (m[5] << 16), m[6] | (m[7] << 16));
}

__device__ __forceinline__ uint4 rne8(const float4& A, const float4& B) {
  float f[8] = {A.x, A.y, A.z, A.w, B.x, B.y, B.z, B.w};
  uint h[8];
#pragma unroll
  for (int i = 0; i < 8; ++i) h[i] = rne16(f[i]);
  return make_uint4(h[0] | (h[1] << 16), h[2] | (h[3] << 16),
                    h[4] | (h[5] << 16), h[6] | (h[7] << 16));
}

// ---------------------------------------------------------------------------
// Bulk f32->bf16: X (2M el), Wq, Wk, Wv, Wo (1M each). 8 el/thread.
// ---------------------------------------------------------------------------
__global__ __launch_bounds__(256) void k_cvtall(
    const float* __restrict__ X, const float* __restrict__ Wq,
    const float* __restrict__ Wk, const float* __restrict__ Wv,
    const float* __restrict__ Wo, ushort* __restrict__ Xb,
    ushort* __restrict__ Wqb, ushort* __restrict__ Wkb,
    ushort* __restrict__ Wvb, ushort* __restrict__ Wob) {
  int i = blockIdx.x * 256 + threadIdx.x;  // chunk index (8 elements)
  const float* src;
  ushort* dst;
  int j;
  if (i < 262144)      { src = X;  dst = Xb;  j = i; }
  else if (i < 393216) { src = Wq; dst = Wqb; j = i - 262144; }
  else if (i < 524288) { src = Wk; dst = Wkb; j = i - 393216; }
  else if (i < 655360) { src = Wv; dst = Wvb; j = i - 524288; }
  else                 { src = Wo; dst = Wob; j = i - 655360; }
  float4 a = *reinterpret_cast<const float4*>(src + j * 8);
  float4 b = *reinterpret_cast<const float4*>(src + j * 8 + 4);
  *reinterpret_cast<uint4*>(dst + j * 8) = rne8(a, b);
}

// ---------------------------------------------------------------------------
// cos/sin table
// ---------------------------------------------------------------------------
__global__ __launch_bounds__(64) void k_cs(float* __restrict__ cs) {
  int s = blockIdx.x * 2 + (threadIdx.x >> 5);
  int p = threadIdx.x & 31;
  float invf = powf(10000.0f, (-2.0f * p) / 64.0f);
  float sn, c;
  sincosf((float)s * invf, &sn, &c);
  cs[s * 64 + 2 * p] = c;
  cs[s * 64 + 2 * p + 1] = sn;
}

// ---------------------------------------------------------------------------
// A[h,t,i] = (1/8) * sum_j proj[h,j] * tpl_norm[h,t,(i-j) mod 64]  -> hi/lo bf16
// ---------------------------------------------------------------------------
__global__ __launch_bounds__(64) void k_prep_A(const float* __restrict__ tpl,
                                               const float* __restrict__ proj,
                                               ushort* __restrict__ Ahh,
                                               ushort* __restrict__ Ahl) {
  int ht = blockIdx.x;
  int h = ht >> 5;
  int lane = threadIdx.x;
  float tv = tpl[ht * 64 + lane];
  float ss = tv * tv;
#pragma unroll
  for (int off = 1; off < 64; off <<= 1) ss += __shfl_xor(ss, off);
  float rn = 1.0f / fmaxf(sqrtf(ss), 1e-12f);
  __shared__ float tn[64];
  tn[lane] = tv * rn;
  __syncthreads();
  float acc = 0.f;
#pragma unroll
  for (int j = 0; j < 64; ++j) acc += proj[h * 64 + j] * tn[(lane - j) & 63];
  float v = acc * 0.125f;
  uint u = __builtin_bit_cast(uint, v);
  uint hi = u >> 16;
  float fh = __builtin_bit_cast(float, u & 0xffff0000u);
  uint lo = __builtin_bit_cast(uint, v - fh) >> 16;
  Ahh[ht * 64 + lane] = (ushort)hi;
  Ahl[ht * 64 + lane] = (ushort)lo;
}

// ---------------------------------------------------------------------------
// QKV GEMM: validated round-8/9 layout + depth-2 pipeline (2 LDS buffers +
// one reg-staged tile in flight: loads for t+2 issued at start of iter t,
// LDS-written at end of iter t+1).
// ---------------------------------------------------------------------------
__global__ __launch_bounds__(256) void k_qkv(
    const ushort* __restrict__ Xb,
    const ushort* __restrict__ Wqb, const ushort* __restrict__ Wkb,
    const ushort* __restrict__ Wvb,
    const ushort* __restrict__ Ahh, const ushort* __restrict__ Ahl,
    const float* __restrict__ cs,
    ushort* __restrict__ Qs, ushort* __restrict__ Ks,
    ushort* __restrict__ Vt) {
  __shared__ __align__(16) char smem[34816];

  const int z = blockIdx.z;
  const ushort* Wm = (z == 0) ? Wqb : (z == 1) ? Wkb : Wvb;
  const int m0 = blockIdx.y * 128;
  const int n0 = blockIdx.x * 64;
  const int h = blockIdx.x;

  const int tid = threadIdx.x;
  const int l = tid & 63;
  const int wid = tid >> 6;
  const int wr = wid >> 1, wc = wid & 1;
  const int l31 = l & 31, lhi = l >> 5;

  const int sr = tid >> 2;
  const int sc = tid & 3;

  const int offA0 = (sr) * 64 + ((sc ^ ((sr >> 1) & 3)) << 4);
  const int offA1 = (sr + 64) * 64 + ((sc ^ (((sr + 64) >> 1) & 3)) << 4);
  const int offB = 8192 + sr * 64 + ((sc ^ ((sr >> 1) & 3)) << 4);

  const ushort* apsrc0 = Xb + (size_t)(m0 + sr) * 1024 + sc * 8;
  const ushort* apsrc1 = Xb + (size_t)(m0 + sr + 64) * 1024 + sc * 8;
  const ushort* bpsrc = Wm + (size_t)(n0 + sr) * 1024 + sc * 8;

  f32x16 acc0 = 0.0f, acc1 = 0.0f;

  // prologue: tile 0 -> LDS buf0; tile 1 -> regs
  {
    *reinterpret_cast<uint4*>(smem + offA0) =
        *reinterpret_cast<const uint4*>(apsrc0);
    *reinterpret_cast<uint4*>(smem + offA1) =
        *reinterpret_cast<const uint4*>(apsrc1);
    *reinterpret_cast<uint4*>(smem + offB) =
        *reinterpret_cast<const uint4*>(bpsrc);
  }
  uint4 ra0 = *reinterpret_cast<const uint4*>(apsrc0 + 32);
  uint4 ra1 = *reinterpret_cast<const uint4*>(apsrc1 + 32);
  uint4 rb = *reinterpret_cast<const uint4*>(bpsrc + 32);
  __syncthreads();

  int cur = 0;
#pragma unroll 4
  for (int t = 0; t < 32; ++t) {
    uint4 na0, na1, nb;
    if (t < 30) {
      const int kn = (t + 2) * 32;
      na0 = *reinterpret_cast<const uint4*>(apsrc0 + kn);
      na1 = *reinterpret_cast<const uint4*>(apsrc1 + kn);
      nb = *reinterpret_cast<const uint4*>(bpsrc + kn);
    }

    const char* base = smem + cur * 12288;
#pragma unroll
    for (int kst = 0; kst < 2; ++kst) {
      FragU ah0, ah1, bh;
      {
        int row = wr * 64 + l31;
        int cc = (kst * 2 + lhi) ^ ((row >> 1) & 3);
        ah0.q = *reinterpret_cast<const uint4*>(base + row * 64 + cc * 16);
      }
      {
        int row = wr * 64 + 32 + l31;
        int cc = (kst * 2 + lhi) ^ ((row >> 1) & 3);
        ah1.q = *reinterpret_cast<const uint4*>(base + row * 64 + cc * 16);
      }
      {
        int brow = wc * 32 + l31;
        int bcc = (kst * 2 + lhi) ^ ((brow >> 1) & 3);
        bh.q = *reinterpret_cast<const uint4*>(base + 8192 + brow * 64 + bcc * 16);
      }
      acc0 = MFMA(ah0.v, bh.v, acc0);
      acc1 = MFMA(ah1.v, bh.v, acc1);
    }

    if (t < 31) {
      char* dst = smem + (cur ^ 1) * 12288;
      *reinterpret_cast<uint4*>(dst + offA0) = ra0;
      *reinterpret_cast<uint4*>(dst + offA1) = ra1;
      *reinterpret_cast<uint4*>(dst + offB) = rb;
      __syncthreads();
      cur ^= 1;
      if (t < 30) { ra0 = na0; ra1 = na1; rb = nb; }
    }
  }

  if (z == 2) {
    int d = wc * 32 + l31;
#pragma unroll
    for (int fm = 0; fm < 2; ++fm) {
      const f32x16& a = fm ? acc1 : acc0;
#pragma unroll
      for (int j = 0; j < 16; ++j) {
        int rl = fm * 32 + (j & 3) + ((j >> 2) & 3) * 8 + 4 * lhi;
        int m = m0 + wr * 64 + rl;
        int b = m >> 10, s = m & 1023;
        Vt[((size_t)((b * 16 + h) * 64 + d)) * 1024 + s] = (ushort)rne16(a[j]);
      }
    }
    return;
  }

  ushort* Sig = (z == 0) ? Qs : Ks;
  float* dmp = reinterpret_cast<float*>(smem);  // [128][68] f32
  __syncthreads();
#pragma unroll
  for (int fm = 0; fm < 2; ++fm) {
    const f32x16& a = fm ? acc1 : acc0;
#pragma unroll
    for (int j = 0; j < 16; ++j) {
      int rl = fm * 32 + (j & 3) + ((j >> 2) & 3) * 8 + 4 * lhi;
      dmp[(wr * 64 + rl) * 68 + wc * 32 + l31] = a[j];
    }
  }
  __syncthreads();

  int srow = wr * 64 + wc * 32 + l31;
  int sq = (m0 + srow) & 1023;
  f32x16 sacc = 0.0f;
#pragma unroll
  for (int kst = 0; kst < 4; ++kst) {
    const float* dp = &dmp[srow * 68 + kst * 16 + lhi * 8];
    float4 x0 = *reinterpret_cast<const float4*>(dp);
    float4 x1 = *reinterpret_cast<const float4*>(dp + 4);
    const float* cp = &cs[sq * 64 + kst * 16 + lhi * 8];
    float4 c0 = *reinterpret_cast<const float4*>(cp);
    float4 c1 = *reinterpret_cast<const float4*>(cp + 4);
    float r[8];
    r[0] = x0.x * c0.x - x0.y * c0.y;
    r[1] = x0.x * c0.y + x0.y * c0.x;
    r[2] = x0.z * c0.z - x0.w * c0.w;
    r[3] = x0.z * c0.w + x0.w * c0.z;
    r[4] = x1.x * c1.x - x1.y * c1.y;
    r[5] = x1.x * c1.y + x1.y * c1.x;
    r[6] = x1.z * c1.z - x1.w * c1.w;
    r[7] = x1.z * c1.w + x1.w * c1.z;
    FragU ah, al;
    split8a(r, ah.q, al.q);
    size_t boff = ((size_t)(h * 32 + l31) * 64 + kst * 16 + lhi * 8);
    FragU bh, bl;
    bh.q = *reinterpret_cast<const uint4*>(Ahh + boff);
    bl.q = *reinterpret_cast<const uint4*>(Ahl + boff);
    sacc = MFMA(al.v, bh.v, sacc);
    sacc = MFMA(ah.v, bl.v, sacc);
    sacc = MFMA(ah.v, bh.v, sacc);
  }
#pragma unroll
  for (int j = 0; j < 16; ++j) {
    float v = sacc[j];
    float ss = v * v;
    ss += __shfl_xor(ss, 1);
    ss += __shfl_xor(ss, 2);
    ss += __shfl_xor(ss, 4);
    ss += __shfl_xor(ss, 8);
    ss += __shfl_xor(ss, 16);
    float rn = 1.0f / fmaxf(sqrtf(ss), 1e-12f);
    int rl = (j & 3) + ((j >> 2) & 3) * 8 + 4 * lhi;
    int m = m0 + wr * 64 + wc * 32 + rl;
    int bb = m >> 10, s2 = m & 1023;
    Sig[(((size_t)(bb * 16 + h)) * 1024 + s2) * 32 + l31] =
        (ushort)rne16(v * rn);
  }
}

// ---------------------------------------------------------------------------
// Split-K MFMA attention (validated round-9), partials now bf16 (halves the
// partial-buffer HBM round-trip; adds one 2^-9 rounding, quadrature-safe).
// ---------------------------------------------------------------------------
__global__ __launch_bounds__(128) void k_attn(const ushort* __restrict__ Qs,
                                              const ushort* __restrict__ Ks,
                                              const ushort* __restrict__ Vt,
                                              ushort* __restrict__ Po,
                                              float* __restrict__ Pd) {
  __shared__ ushort plds[2][32][68];

  const int tid = threadIdx.x;
  const int l = tid & 63;
  const int wid = tid >> 6;
  const int l31 = l & 31, lhi = l >> 5;
  const int bh = blockIdx.y;
  const int z = blockIdx.z;
  const int q0 = blockIdx.x * 64 + wid * 32;

  FragU aq0, aq1;
  {
    const ushort* qp = Qs + ((size_t)bh * 1024 + q0 + l31) * 32 + lhi * 8;
    aq0.q = *reinterpret_cast<const uint4*>(qp);
    aq1.q = *reinterpret_cast<const uint4*>(qp + 16);
  }

  const ushort* kbase = Ks + (size_t)bh * 1024 * 32;
  const ushort* vbase = Vt + (size_t)bh * 64 * 1024;

  f32x16 oacc0 = 0.0f, oacc1 = 0.0f;
  float pden[16];
#pragma unroll
  for (int r = 0; r < 16; ++r) pden[r] = 0.f;

  for (int kt = z * 4; kt < z * 4 + 4; ++kt) {
    const int k0 = kt * 64;
    f32x16 sacc[2];
    sacc[0] = 0.0f;
    sacc[1] = 0.0f;
#pragma unroll
    for (int nt = 0; nt < 2; ++nt) {
      const ushort* kp = kbase + (size_t)(k0 + nt * 32 + l31) * 32 + lhi * 8;
      FragU b0, b1;
      b0.q = *reinterpret_cast<const uint4*>(kp);
      b1.q = *reinterpret_cast<const uint4*>(kp + 16);
      sacc[nt] = MFMA(aq0.v, b0.v, sacc[nt]);
      sacc[nt] = MFMA(aq1.v, b1.v, sacc[nt]);
    }
#pragma unroll
    for (int nt = 0; nt < 2; ++nt) {
#pragma unroll
      for (int r = 0; r < 16; ++r) {
        float e = __expf(sacc[nt][r] * SCALE_F);
        pden[r] += e;
        int q = (r & 3) + ((r >> 2) << 3) + 4 * lhi;
        plds[wid][q][nt * 32 + l31] = (ushort)rne16(e);
      }
    }
    __builtin_amdgcn_wave_barrier();
#pragma unroll
    for (int kst = 0; kst < 4; ++kst) {
      FragU ap;
      const ushort* pp = &plds[wid][l31][kst * 16 + lhi * 8];
      uint2 plo = *reinterpret_cast<const uint2*>(pp);
      uint2 phi = *reinterpret_cast<const uint2*>(pp + 4);
      ap.q = make_uint4(plo.x, plo.y, phi.x, phi.y);
      FragU bv0, bv1;
      const ushort* vp0 = vbase + (size_t)l31 * 1024 + k0 + kst * 16 + lhi * 8;
      bv0.q = *reinterpret_cast<const uint4*>(vp0);
      bv1.q = *reinterpret_cast<const uint4*>(vp0 + 32 * 1024);
      oacc0 = MFMA(ap.v, bv0.v, oacc0);
      oacc1 = MFMA(ap.v, bv1.v, oacc1);
    }
  }

#pragma unroll
  for (int r = 0; r < 16; ++r) {
    float s = pden[r];
    s += __shfl_xor(s, 1);
    s += __shfl_xor(s, 2);
    s += __shfl_xor(s, 4);
    s += __shfl_xor(s, 8);
    s += __shfl_xor(s, 16);
    pden[r] = s;
  }

  const size_t zb = (size_t)z * 32 + bh;
#pragma unroll
  for (int r = 0; r < 16; ++r) {
    int q = q0 + (r & 3) + ((r >> 2) << 3) + 4 * lhi;
    size_t row = zb * 1024 + q;
    Po[row * 64 + l31] = (ushort)rne16(oacc0[r]);
    Po[row * 64 + 32 + l31] = (ushort)rne16(oacc1[r]);
    if (l31 == 0) Pd[row] = pden[r];
  }
}

// ---------------------------------------------------------------------------
// Merge 4 split-K partials: O = (sum_z Po) / (sum_z Pd), write bf16 obuf.
// ---------------------------------------------------------------------------
__global__ __launch_bounds__(256) void k_attnred(const ushort* __restrict__ Po,
                                                 const float* __restrict__ Pd,
                                                 ushort* __restrict__ O) {
  int idx = blockIdx.x * 4 + (threadIdx.x >> 6);  // row id: bh*1024 + q
  int d = threadIdx.x & 63;
  float den = 0.f, val = 0.f;
#pragma unroll
  for (int zc = 0; zc < 4; ++zc) {
    size_t row = (size_t)zc * 32768 + idx;
    den += Pd[row];
    val += bf2f(Po[row * 64 + d]);
  }
  int bh = idx >> 10, q = idx & 1023;
  int b = bh >> 4, h = bh & 15;
  O[((size_t)(b * 1024 + q)) * 1024 + h * 64 + d] = (ushort)rne16(val / den);
}

// ---------------------------------------------------------------------------
// Single-pass attention (round-8 validated) — fallback for small ws.
// ---------------------------------------------------------------------------
__global__ __launch_bounds__(128) void k_attn_mono(const ushort* __restrict__ Qs,
                                                   const ushort* __restrict__ Ks,
                                                   const ushort* __restrict__ Vt,
                                                   ushort* __restrict__ O) {
  __shared__ ushort plds[2][32][68];

  const int tid = threadIdx.x;
  const int l = tid & 63;
  const int wid = tid >> 6;
  const int l31 = l & 31, lhi = l >> 5;
  const int bh = blockIdx.y;
  const int q0 = blockIdx.x * 64 + wid * 32;

  FragU aq0, aq1;
  {
    const ushort* qp = Qs + ((size_t)bh * 1024 + q0 + l31) * 32 + lhi * 8;
    aq0.q = *reinterpret_cast<const uint4*>(qp);
    aq1.q = *reinterpret_cast<const uint4*>(qp + 16);
  }

  const ushort* kbase = Ks + (size_t)bh * 1024 * 32;
  const ushort* vbase = Vt + (size_t)bh * 64 * 1024;

  f32x16 oacc0 = 0.0f, oacc1 = 0.0f;
  float pden[16];
#pragma unroll
  for (int r = 0; r < 16; ++r) pden[r] = 0.f;

  for (int kt = 0; kt < 16; ++kt) {
    const int k0 = kt * 64;
    f32x16 sacc[2];
    sacc[0] = 0.0f;
    sacc[1] = 0.0f;
#pragma unroll
    for (int nt = 0; nt < 2; ++nt) {
      const ushort* kp = kbase + (size_t)(k0 + nt * 32 + l31) * 32 + lhi * 8;
      FragU b0, b1;
      b0.q = *reinterpret_cast<const uint4*>(kp);
      b1.q = *reinterpret_cast<const uint4*>(kp + 16);
      sacc[nt] = MFMA(aq0.v, b0.v, sacc[nt]);
      sacc[nt] = MFMA(aq1.v, b1.v, sacc[nt]);
    }
#pragma unroll
    for (int nt = 0; nt < 2; ++nt) {
#pragma unroll
      for (int r = 0; r < 16; ++r) {
        float e = __expf(sacc[nt][r] * SCALE_F);
        pden[r] += e;
        int q = (r & 3) + ((r >> 2) << 3) + 4 * lhi;
        plds[wid][q][nt * 32 + l31] = (ushort)rne16(e);
      }
    }
    __builtin_amdgcn_wave_barrier();
#pragma unroll
    for (int kst = 0; kst < 4; ++kst) {
      FragU ap;
      const ushort* pp = &plds[wid][l31][kst * 16 + lhi * 8];
      uint2 plo = *reinterpret_cast<const uint2*>(pp);
      uint2 phi = *reinterpret_cast<const uint2*>(pp + 4);
      ap.q = make_uint4(plo.x, plo.y, phi.x, phi.y);
      FragU bv0, bv1;
      const ushort* vp0 = vbase + (size_t)l31 * 1024 + k0 + kst * 16 + lhi * 8;
      bv0.q = *reinterpret_cast<const uint4*>(vp0);
      bv1.q = *reinterpret_cast<const uint4*>(vp0 + 32 * 1024);
      oacc0 = MFMA(ap.v, bv0.v, oacc0);
      oacc1 = MFMA(ap.v, bv1.v, oacc1);
    }
  }

#pragma unroll
  for (int r = 0; r < 16; ++r) {
    float s = pden[r];
    s += __shfl_xor(s, 1);
    s += __shfl_xor(s, 2);
    s += __shfl_xor(s, 4);
    s += __shfl_xor(s, 8);
    s += __shfl_xor(s, 16);
    pden[r] = 1.0f / s;
  }

  const int b = bh >> 4, h = bh & 15;
#pragma unroll
  for (int r = 0; r < 16; ++r) {
    int q = q0 + (r & 3) + ((r >> 2) << 3) + 4 * lhi;
    size_t row = ((size_t)b * 1024 + q) * 1024 + h * 64;
    O[row + l31] = (ushort)rne16(oacc0[r] * pden[r]);
    O[row + 32 + l31] = (ushort)rne16(oacc1[r] * pden[r]);
  }
}

// ---------------------------------------------------------------------------
// Final projection: validated 64x64 tile + depth-2 pipeline.
// ---------------------------------------------------------------------------
__global__ __launch_bounds__(256) void k_final(const ushort* __restrict__ Xb,
                                               const ushort* __restrict__ Wb,
                                               float* __restrict__ Y) {
  __shared__ __align__(16) char smem[16384];

  const int m0 = blockIdx.y * 64;
  const int n0 = blockIdx.x * 64;
  const int tid = threadIdx.x;
  const int l = tid & 63;
  const int wid = tid >> 6;
  const int wr = wid >> 1, wc = wid & 1;
  const int l31 = l & 31, lhi = l >> 5;
  const int sr = tid >> 2;
  const int sc = tid & 3;

  const int offA = sr * 64 + ((sc ^ ((sr >> 1) & 3)) << 4);
  const int offB = 4096 + offA;
  const ushort* apsrc = Xb + (size_t)(m0 + sr) * 1024 + sc * 8;
  const ushort* bpsrc = Wb + (size_t)(n0 + sr) * 1024 + sc * 8;

  f32x16 acc = 0.0f;

  {
    *reinterpret_cast<uint4*>(smem + offA) =
        *reinterpret_cast<const uint4*>(apsrc);
    *reinterpret_cast<uint4*>(smem + offB) =
        *reinterpret_cast<const uint4*>(bpsrc);
  }
  uint4 ra = *reinterpret_cast<const uint4*>(apsrc + 32);
  uint4 rb = *reinterpret_cast<const uint4*>(bpsrc + 32);
  __syncthreads();

  int cur = 0;
#pragma unroll 4
  for (int t = 0; t < 32; ++t) {
    uint4 na, nb;
    if (t < 30) {
      const int kn = (t + 2) * 32;
      na = *reinterpret_cast<const uint4*>(apsrc + kn);
      nb = *reinterpret_cast<const uint4*>(bpsrc + kn);
    }

    const char* base = smem + cur * 8192;
#pragma unroll
    for (int kst = 0; kst < 2; ++kst) {
      FragU ah, bh;
      int row = wr * 32 + l31;
      int cc = (kst * 2 + lhi) ^ ((row >> 1) & 3);
      ah.q = *reinterpret_cast<const uint4*>(base + row * 64 + cc * 16);
      int brow = wc * 32 + l31;
      int bcc = (kst * 2 + lhi) ^ ((brow >> 1) & 3);
      bh.q = *reinterpret_cast<const uint4*>(base + 4096 + brow * 64 + bcc * 16);
      acc = MFMA(ah.v, bh.v, acc);
    }

    if (t < 31) {
      char* dst = smem + (cur ^ 1) * 8192;
      *reinterpret_cast<uint4*>(dst + offA) = ra;
      *reinterpret_cast<uint4*>(dst + offB) = rb;
      __syncthreads();
      cur ^= 1;
      if (t < 30) { ra = na; rb = nb; }
    }
  }

#pragma unroll
  for (int j = 0; j < 16; ++j) {
    int rl = (j & 3) + ((j >> 2) & 3) * 8 + 4 * lhi;
    int m = m0 + wr * 32 + rl;
    Y[(size_t)m * 1024 + n0 + wc * 32 + l31] = acc[j];
  }
}

// ---------------------------------------------------------------------------
extern "C" void kernel_launch(void* const* d_in, const int* in_sizes, int n_in,
                              void* d_out, int out_size, void* d_ws,
                              size_t ws_size, hipStream_t stream) {
  const float* x = (const float*)d_in[0];
  const float* Wq = (const float*)d_in[1];
  const float* Wk = (const float*)d_in[2];
  const float* Wv = (const float*)d_in[3];
  const float* Wo = (const float*)d_in[4];
  const float* tpl = (const float*)d_in[5];
  const float* proj = (const float*)d_in[6];
  float* out = (float*)d_out;

  char* ws = (char*)d_ws;
  size_t off = 0;
  auto alloc = [&](size_t bytes) {
    void* p = ws + off;
    off += (bytes + 255) & ~(size_t)255;
    return p;
  };

  const size_t MB = 1024 * 1024;
  bool huge = ws_size >= 64 * MB;   // evidence (256MB ws poison): active path
  bool big = ws_size >= 22 * MB;

  ushort *Xb, *Wvb, *obuf;
  float* cs;
  ushort *Ahh, *Ahl, *Wqb, *Wkb, *Wob, *qs, *ks, *vt;
  ushort* Po = nullptr;
  float* Pd = nullptr;

  if (big || huge) {
    Xb = (ushort*)alloc(4 * MB);
    cs = (float*)alloc((size_t)1024 * 64 * 4);
    Ahh = (ushort*)alloc((size_t)16 * 32 * 64 * 2);
    Ahl = (ushort*)alloc((size_t)16 * 32 * 64 * 2);
    Wqb = (ushort*)alloc(2 * MB);
    Wkb = (ushort*)alloc(2 * MB);
    Wvb = (ushort*)alloc(2 * MB);
    Wob = (ushort*)alloc(2 * MB);
    qs = (ushort*)alloc(2 * MB);
    ks = (ushort*)alloc(2 * MB);
    vt = (ushort*)alloc(4 * MB);
    if (huge) {
      Po = (ushort*)alloc(16 * MB);
      Pd = (float*)alloc((size_t)4 * 32768 * 4);
    }
    obuf = Xb;  // Xb dead after k_qkv
  } else {
    cs = (float*)alloc((size_t)1024 * 64 * 4);
    Ahh = (ushort*)alloc((size_t)16 * 32 * 64 * 2);
    Ahl = (ushort*)alloc((size_t)16 * 32 * 64 * 2);
    Wqb = (ushort*)alloc(2 * MB);
    Wkb = (ushort*)alloc(2 * MB);
    Wob = (ushort*)alloc(2 * MB);
    qs = (ushort*)alloc(2 * MB);
    ks = (ushort*)alloc(2 * MB);
    vt = (ushort*)alloc(4 * MB);
    obuf = (ushort*)ws;
    Xb = (ushort*)d_out;
    Wvb = (ushort*)((char*)d_out + 4 * MB);
  }

  k_cvtall<<<dim3(3072), dim3(256), 0, stream>>>(x, Wq, Wk, Wv, Wo, Xb, Wqb,
                                                 Wkb, Wvb, Wob);
  k_cs<<<dim3(512), dim3(64), 0, stream>>>(cs);
  k_prep_A<<<dim3(512), dim3(64), 0, stream>>>(tpl, proj, Ahh, Ahl);
  k_qkv<<<dim3(16, 16, 3), dim3(256), 0, stream>>>(Xb, Wqb, Wkb, Wvb, Ahh, Ahl,
                                                   cs, qs, ks, vt);
  if (huge) {
    k_attn<<<dim3(16, 32, 4), dim3(128), 0, stream>>>(qs, ks, vt, Po, Pd);
    k_attnred<<<dim3(8192), dim3(256), 0, stream>>>(Po, Pd, obuf);
  } else {
    k_attn_mono<<<dim3(16, 32), dim3(128), 0, stream>>>(qs, ks, vt, obuf);
  }
  k_final<<<dim3(16, 32), dim3(256), 0, stream>>>(obuf, Wob, out);
}

// Round 11
// 86.534 us; speedup vs baseline: 1.8227x; 1.0482x over previous
//
#include <hip/hip_runtime.h>
#include <math.h>

#define S_ 1024
#define T_ 32
#define SCALE_F 0.7071067811865476f

typedef unsigned int uint;
typedef unsigned short ushort;
typedef __bf16 bf16x8 __attribute__((ext_vector_type(8)));
typedef float f32x16 __attribute__((ext_vector_type(16)));

union FragU { uint4 q; bf16x8 v; };

#define MFMA(a, b, c) __builtin_amdgcn_mfma_f32_32x32x16_bf16((a), (b), (c), 0, 0, 0)

__device__ __forceinline__ uint rne16(float f) {
  uint u = __builtin_bit_cast(uint, f);
  u += 0x7fffu + ((u >> 16) & 1u);
  return u >> 16;
}

__device__ __forceinline__ float bf2f(ushort u) {
  return __builtin_bit_cast(float, ((uint)u) << 16);
}

__device__ __forceinline__ void split8a(const float* f, uint4& hi, uint4& lo) {
  uint h[8], m[8];
#pragma unroll
  for (int i = 0; i < 8; ++i) {
    uint u = __builtin_bit_cast(uint, f[i]);
    h[i] = u >> 16;
    float fh = __builtin_bit_cast(float, u & 0xffff0000u);
    m[i] = __builtin_bit_cast(uint, f[i] - fh) >> 16;
  }
  hi = make_uint4(h[0] | (h[1] << 16), h[2] | (h[3] << 16),
                  h[4] | (h[5] << 16), h[6] | (h[7] << 16));
  lo = make_uint4(m[0] | (m[1] << 16), m[2] | (m[3] << 16),
                  m[4] | (m[5] << 16), m[6] | (m[7] << 16));
}

__device__ __forceinline__ uint4 rne8(const float4& A, const float4& B) {
  float f[8] = {A.x, A.y, A.z, A.w, B.x, B.y, B.z, B.w};
  uint h[8];
#pragma unroll
  for (int i = 0; i < 8; ++i) h[i] = rne16(f[i]);
  return make_uint4(h[0] | (h[1] << 16), h[2] | (h[3] << 16),
                    h[4] | (h[5] << 16), h[6] | (h[7] << 16));
}

// ---------------------------------------------------------------------------
// Merged prep: blocks [0,3072) bulk f32->bf16 cvt; [3072,3200) cos/sin table;
// [3200,3328) A-matrix build (4 ht per block, one per wave).
// ---------------------------------------------------------------------------
__global__ __launch_bounds__(256) void k_prep(
    const float* __restrict__ X, const float* __restrict__ Wq,
    const float* __restrict__ Wk, const float* __restrict__ Wv,
    const float* __restrict__ Wo, const float* __restrict__ tpl,
    const float* __restrict__ proj, ushort* __restrict__ Xb,
    ushort* __restrict__ Wqb, ushort* __restrict__ Wkb,
    ushort* __restrict__ Wvb, ushort* __restrict__ Wob,
    float* __restrict__ cs, ushort* __restrict__ Ahh,
    ushort* __restrict__ Ahl) {
  const int bid = blockIdx.x;
  const int tid = threadIdx.x;

  if (bid < 3072) {
    int i = bid * 256 + tid;
    const float* src;
    ushort* dst;
    int j;
    if (i < 262144)      { src = X;  dst = Xb;  j = i; }
    else if (i < 393216) { src = Wq; dst = Wqb; j = i - 262144; }
    else if (i < 524288) { src = Wk; dst = Wkb; j = i - 393216; }
    else if (i < 655360) { src = Wv; dst = Wvb; j = i - 524288; }
    else                 { src = Wo; dst = Wob; j = i - 655360; }
    float4 a = *reinterpret_cast<const float4*>(src + j * 8);
    float4 b = *reinterpret_cast<const float4*>(src + j * 8 + 4);
    *reinterpret_cast<uint4*>(dst + j * 8) = rne8(a, b);
    return;
  }

  if (bid < 3200) {
    int j = (bid - 3072) * 256 + tid;  // 0..32767
    int s = j >> 5, p = j & 31;
    float invf = powf(10000.0f, (-2.0f * p) / 64.0f);
    float sn, c;
    sincosf((float)s * invf, &sn, &c);
    cs[s * 64 + 2 * p] = c;
    cs[s * 64 + 2 * p + 1] = sn;
    return;
  }

  // A-matrix: ht = (bid-3200)*4 + wave
  {
    __shared__ float tn[4][64];
    int wid = tid >> 6, lane = tid & 63;
    int ht = (bid - 3200) * 4 + wid;
    int h = ht >> 5;
    float tv = tpl[ht * 64 + lane];
    float ss = tv * tv;
#pragma unroll
    for (int off2 = 1; off2 < 64; off2 <<= 1) ss += __shfl_xor(ss, off2);
    float rn = 1.0f / fmaxf(sqrtf(ss), 1e-12f);
    tn[wid][lane] = tv * rn;
    __syncthreads();
    float acc = 0.f;
#pragma unroll
    for (int j2 = 0; j2 < 64; ++j2)
      acc += proj[h * 64 + j2] * tn[wid][(lane - j2) & 63];
    float v = acc * 0.125f;
    uint u = __builtin_bit_cast(uint, v);
    uint hi = u >> 16;
    float fh = __builtin_bit_cast(float, u & 0xffff0000u);
    uint lo = __builtin_bit_cast(uint, v - fh) >> 16;
    Ahh[ht * 64 + lane] = (ushort)hi;
    Ahl[ht * 64 + lane] = (ushort)lo;
  }
}

// ---------------------------------------------------------------------------
// QKV GEMM (validated round-10): depth-2 pipeline, 2 LDS buffers + reg stage.
// ---------------------------------------------------------------------------
__global__ __launch_bounds__(256) void k_qkv(
    const ushort* __restrict__ Xb,
    const ushort* __restrict__ Wqb, const ushort* __restrict__ Wkb,
    const ushort* __restrict__ Wvb,
    const ushort* __restrict__ Ahh, const ushort* __restrict__ Ahl,
    const float* __restrict__ cs,
    ushort* __restrict__ Qs, ushort* __restrict__ Ks,
    ushort* __restrict__ Vt) {
  __shared__ __align__(16) char smem[34816];

  const int z = blockIdx.z;
  const ushort* Wm = (z == 0) ? Wqb : (z == 1) ? Wkb : Wvb;
  const int m0 = blockIdx.y * 128;
  const int n0 = blockIdx.x * 64;
  const int h = blockIdx.x;

  const int tid = threadIdx.x;
  const int l = tid & 63;
  const int wid = tid >> 6;
  const int wr = wid >> 1, wc = wid & 1;
  const int l31 = l & 31, lhi = l >> 5;

  const int sr = tid >> 2;
  const int sc = tid & 3;

  const int offA0 = (sr) * 64 + ((sc ^ ((sr >> 1) & 3)) << 4);
  const int offA1 = (sr + 64) * 64 + ((sc ^ (((sr + 64) >> 1) & 3)) << 4);
  const int offB = 8192 + sr * 64 + ((sc ^ ((sr >> 1) & 3)) << 4);

  const ushort* apsrc0 = Xb + (size_t)(m0 + sr) * 1024 + sc * 8;
  const ushort* apsrc1 = Xb + (size_t)(m0 + sr + 64) * 1024 + sc * 8;
  const ushort* bpsrc = Wm + (size_t)(n0 + sr) * 1024 + sc * 8;

  f32x16 acc0 = 0.0f, acc1 = 0.0f;

  {
    *reinterpret_cast<uint4*>(smem + offA0) =
        *reinterpret_cast<const uint4*>(apsrc0);
    *reinterpret_cast<uint4*>(smem + offA1) =
        *reinterpret_cast<const uint4*>(apsrc1);
    *reinterpret_cast<uint4*>(smem + offB) =
        *reinterpret_cast<const uint4*>(bpsrc);
  }
  uint4 ra0 = *reinterpret_cast<const uint4*>(apsrc0 + 32);
  uint4 ra1 = *reinterpret_cast<const uint4*>(apsrc1 + 32);
  uint4 rb = *reinterpret_cast<const uint4*>(bpsrc + 32);
  __syncthreads();

  int cur = 0;
#pragma unroll 4
  for (int t = 0; t < 32; ++t) {
    uint4 na0, na1, nb;
    if (t < 30) {
      const int kn = (t + 2) * 32;
      na0 = *reinterpret_cast<const uint4*>(apsrc0 + kn);
      na1 = *reinterpret_cast<const uint4*>(apsrc1 + kn);
      nb = *reinterpret_cast<const uint4*>(bpsrc + kn);
    }

    const char* base = smem + cur * 12288;
#pragma unroll
    for (int kst = 0; kst < 2; ++kst) {
      FragU ah0, ah1, bh;
      {
        int row = wr * 64 + l31;
        int cc = (kst * 2 + lhi) ^ ((row >> 1) & 3);
        ah0.q = *reinterpret_cast<const uint4*>(base + row * 64 + cc * 16);
      }
      {
        int row = wr * 64 + 32 + l31;
        int cc = (kst * 2 + lhi) ^ ((row >> 1) & 3);
        ah1.q = *reinterpret_cast<const uint4*>(base + row * 64 + cc * 16);
      }
      {
        int brow = wc * 32 + l31;
        int bcc = (kst * 2 + lhi) ^ ((brow >> 1) & 3);
        bh.q = *reinterpret_cast<const uint4*>(base + 8192 + brow * 64 + bcc * 16);
      }
      acc0 = MFMA(ah0.v, bh.v, acc0);
      acc1 = MFMA(ah1.v, bh.v, acc1);
    }

    if (t < 31) {
      char* dst = smem + (cur ^ 1) * 12288;
      *reinterpret_cast<uint4*>(dst + offA0) = ra0;
      *reinterpret_cast<uint4*>(dst + offA1) = ra1;
      *reinterpret_cast<uint4*>(dst + offB) = rb;
      __syncthreads();
      cur ^= 1;
      if (t < 30) { ra0 = na0; ra1 = na1; rb = nb; }
    }
  }

  if (z == 2) {
    int d = wc * 32 + l31;
#pragma unroll
    for (int fm = 0; fm < 2; ++fm) {
      const f32x16& a = fm ? acc1 : acc0;
#pragma unroll
      for (int j = 0; j < 16; ++j) {
        int rl = fm * 32 + (j & 3) + ((j >> 2) & 3) * 8 + 4 * lhi;
        int m = m0 + wr * 64 + rl;
        int b = m >> 10, s = m & 1023;
        Vt[((size_t)((b * 16 + h) * 64 + d)) * 1024 + s] = (ushort)rne16(a[j]);
      }
    }
    return;
  }

  ushort* Sig = (z == 0) ? Qs : Ks;
  float* dmp = reinterpret_cast<float*>(smem);  // [128][68] f32
  __syncthreads();
#pragma unroll
  for (int fm = 0; fm < 2; ++fm) {
    const f32x16& a = fm ? acc1 : acc0;
#pragma unroll
    for (int j = 0; j < 16; ++j) {
      int rl = fm * 32 + (j & 3) + ((j >> 2) & 3) * 8 + 4 * lhi;
      dmp[(wr * 64 + rl) * 68 + wc * 32 + l31] = a[j];
    }
  }
  __syncthreads();

  int srow = wr * 64 + wc * 32 + l31;
  int sq = (m0 + srow) & 1023;
  f32x16 sacc = 0.0f;
#pragma unroll
  for (int kst = 0; kst < 4; ++kst) {
    const float* dp = &dmp[srow * 68 + kst * 16 + lhi * 8];
    float4 x0 = *reinterpret_cast<const float4*>(dp);
    float4 x1 = *reinterpret_cast<const float4*>(dp + 4);
    const float* cp = &cs[sq * 64 + kst * 16 + lhi * 8];
    float4 c0 = *reinterpret_cast<const float4*>(cp);
    float4 c1 = *reinterpret_cast<const float4*>(cp + 4);
    float r[8];
    r[0] = x0.x * c0.x - x0.y * c0.y;
    r[1] = x0.x * c0.y + x0.y * c0.x;
    r[2] = x0.z * c0.z - x0.w * c0.w;
    r[3] = x0.z * c0.w + x0.w * c0.z;
    r[4] = x1.x * c1.x - x1.y * c1.y;
    r[5] = x1.x * c1.y + x1.y * c1.x;
    r[6] = x1.z * c1.z - x1.w * c1.w;
    r[7] = x1.z * c1.w + x1.w * c1.z;
    FragU ah, al;
    split8a(r, ah.q, al.q);
    size_t boff = ((size_t)(h * 32 + l31) * 64 + kst * 16 + lhi * 8);
    FragU bh, bl;
    bh.q = *reinterpret_cast<const uint4*>(Ahh + boff);
    bl.q = *reinterpret_cast<const uint4*>(Ahl + boff);
    sacc = MFMA(al.v, bh.v, sacc);
    sacc = MFMA(ah.v, bl.v, sacc);
    sacc = MFMA(ah.v, bh.v, sacc);
  }
#pragma unroll
  for (int j = 0; j < 16; ++j) {
    float v = sacc[j];
    float ss = v * v;
    ss += __shfl_xor(ss, 1);
    ss += __shfl_xor(ss, 2);
    ss += __shfl_xor(ss, 4);
    ss += __shfl_xor(ss, 8);
    ss += __shfl_xor(ss, 16);
    float rn = 1.0f / fmaxf(sqrtf(ss), 1e-12f);
    int rl = (j & 3) + ((j >> 2) & 3) * 8 + 4 * lhi;
    int m = m0 + wr * 64 + wc * 32 + rl;
    int bb = m >> 10, s2 = m & 1023;
    Sig[(((size_t)(bb * 16 + h)) * 1024 + s2) * 32 + l31] =
        (ushort)rne16(v * rn);
  }
}

// ---------------------------------------------------------------------------
// Split-K MFMA attention with async-stage prefetch (T14):
//  - V loads for kt issued at iteration top (consumed in PV, hidden under
//    QK MFMA + exp + LDS);
//  - K loads for kt+1 issued right after QK MFMAs (hidden under exp + PV).
// Math identical to validated round-10 kernel.
// ---------------------------------------------------------------------------
__global__ __launch_bounds__(128) void k_attn(const ushort* __restrict__ Qs,
                                              const ushort* __restrict__ Ks,
                                              const ushort* __restrict__ Vt,
                                              ushort* __restrict__ Po,
                                              float* __restrict__ Pd) {
  __shared__ ushort plds[2][32][68];

  const int tid = threadIdx.x;
  const int l = tid & 63;
  const int wid = tid >> 6;
  const int l31 = l & 31, lhi = l >> 5;
  const int bh = blockIdx.y;
  const int z = blockIdx.z;
  const int q0 = blockIdx.x * 64 + wid * 32;

  FragU aq0, aq1;
  {
    const ushort* qp = Qs + ((size_t)bh * 1024 + q0 + l31) * 32 + lhi * 8;
    aq0.q = *reinterpret_cast<const uint4*>(qp);
    aq1.q = *reinterpret_cast<const uint4*>(qp + 16);
  }

  const ushort* kbase = Ks + (size_t)bh * 1024 * 32;
  const ushort* vbase = Vt + (size_t)bh * 64 * 1024;

  f32x16 oacc0 = 0.0f, oacc1 = 0.0f;
  float pden[16];
#pragma unroll
  for (int r = 0; r < 16; ++r) pden[r] = 0.f;

  const int ktBeg = z * 4;
  // prologue: K frags for first kt
  FragU kc00, kc01, kc10, kc11;
  {
    const ushort* kp0 = kbase + (size_t)(ktBeg * 64 + l31) * 32 + lhi * 8;
    const ushort* kp1 = kbase + (size_t)(ktBeg * 64 + 32 + l31) * 32 + lhi * 8;
    kc00.q = *reinterpret_cast<const uint4*>(kp0);
    kc01.q = *reinterpret_cast<const uint4*>(kp0 + 16);
    kc10.q = *reinterpret_cast<const uint4*>(kp1);
    kc11.q = *reinterpret_cast<const uint4*>(kp1 + 16);
  }

#pragma unroll
  for (int ki = 0; ki < 4; ++ki) {
    const int kt = ktBeg + ki;
    const int k0 = kt * 64;

    // ---- issue V loads for this kt (consumed in PV below) ----
    FragU vv00, vv01, vv10, vv11, vv20, vv21, vv30, vv31;
    {
      const ushort* vp = vbase + (size_t)l31 * 1024 + k0 + lhi * 8;
      vv00.q = *reinterpret_cast<const uint4*>(vp);
      vv01.q = *reinterpret_cast<const uint4*>(vp + 32 * 1024);
      vv10.q = *reinterpret_cast<const uint4*>(vp + 16);
      vv11.q = *reinterpret_cast<const uint4*>(vp + 16 + 32 * 1024);
      vv20.q = *reinterpret_cast<const uint4*>(vp + 32);
      vv21.q = *reinterpret_cast<const uint4*>(vp + 32 + 32 * 1024);
      vv30.q = *reinterpret_cast<const uint4*>(vp + 48);
      vv31.q = *reinterpret_cast<const uint4*>(vp + 48 + 32 * 1024);
    }

    // ---- QK^T scores ----
    f32x16 sacc0 = 0.0f, sacc1 = 0.0f;
    sacc0 = MFMA(aq0.v, kc00.v, sacc0);
    sacc0 = MFMA(aq1.v, kc01.v, sacc0);
    sacc1 = MFMA(aq0.v, kc10.v, sacc1);
    sacc1 = MFMA(aq1.v, kc11.v, sacc1);

    // ---- issue K loads for kt+1 ----
    FragU kn00, kn01, kn10, kn11;
    if (ki < 3) {
      const ushort* kp0 = kbase + (size_t)((kt + 1) * 64 + l31) * 32 + lhi * 8;
      const ushort* kp1 =
          kbase + (size_t)((kt + 1) * 64 + 32 + l31) * 32 + lhi * 8;
      kn00.q = *reinterpret_cast<const uint4*>(kp0);
      kn01.q = *reinterpret_cast<const uint4*>(kp0 + 16);
      kn10.q = *reinterpret_cast<const uint4*>(kp1);
      kn11.q = *reinterpret_cast<const uint4*>(kp1 + 16);
    }

    // ---- exp -> den + bf16 P to per-wave LDS ----
#pragma unroll
    for (int r = 0; r < 16; ++r) {
      float e0 = __expf(sacc0[r] * SCALE_F);
      float e1 = __expf(sacc1[r] * SCALE_F);
      pden[r] += e0 + e1;
      int q = (r & 3) + ((r >> 2) << 3) + 4 * lhi;
      plds[wid][q][l31] = (ushort)rne16(e0);
      plds[wid][q][32 + l31] = (ushort)rne16(e1);
    }
    __builtin_amdgcn_wave_barrier();

    // ---- PV ----
#pragma unroll
    for (int kst = 0; kst < 4; ++kst) {
      FragU ap;
      const ushort* pp = &plds[wid][l31][kst * 16 + lhi * 8];
      uint2 plo = *reinterpret_cast<const uint2*>(pp);
      uint2 phi = *reinterpret_cast<const uint2*>(pp + 4);
      ap.q = make_uint4(plo.x, plo.y, phi.x, phi.y);
      const FragU& b0 = (kst == 0) ? vv00 : (kst == 1) ? vv10 : (kst == 2) ? vv20 : vv30;
      const FragU& b1 = (kst == 0) ? vv01 : (kst == 1) ? vv11 : (kst == 2) ? vv21 : vv31;
      oacc0 = MFMA(ap.v, b0.v, oacc0);
      oacc1 = MFMA(ap.v, b1.v, oacc1);
    }

    if (ki < 3) { kc00 = kn00; kc01 = kn01; kc10 = kn10; kc11 = kn11; }
  }

#pragma unroll
  for (int r = 0; r < 16; ++r) {
    float s = pden[r];
    s += __shfl_xor(s, 1);
    s += __shfl_xor(s, 2);
    s += __shfl_xor(s, 4);
    s += __shfl_xor(s, 8);
    s += __shfl_xor(s, 16);
    pden[r] = s;
  }

  const size_t zb = (size_t)z * 32 + bh;
#pragma unroll
  for (int r = 0; r < 16; ++r) {
    int q = q0 + (r & 3) + ((r >> 2) << 3) + 4 * lhi;
    size_t row = zb * 1024 + q;
    Po[row * 64 + l31] = (ushort)rne16(oacc0[r]);
    Po[row * 64 + 32 + l31] = (ushort)rne16(oacc1[r]);
    if (l31 == 0) Pd[row] = pden[r];
  }
}

// ---------------------------------------------------------------------------
// Merge 4 split-K partials: O = (sum_z Po) / (sum_z Pd), write bf16 obuf.
// ---------------------------------------------------------------------------
__global__ __launch_bounds__(256) void k_attnred(const ushort* __restrict__ Po,
                                                 const float* __restrict__ Pd,
                                                 ushort* __restrict__ O) {
  int idx = blockIdx.x * 4 + (threadIdx.x >> 6);  // row id: bh*1024 + q
  int d = threadIdx.x & 63;
  float den = 0.f, val = 0.f;
#pragma unroll
  for (int zc = 0; zc < 4; ++zc) {
    size_t row = (size_t)zc * 32768 + idx;
    den += Pd[row];
    val += bf2f(Po[row * 64 + d]);
  }
  int bh = idx >> 10, q = idx & 1023;
  int b = bh >> 4, h = bh & 15;
  O[((size_t)(b * 1024 + q)) * 1024 + h * 64 + d] = (ushort)rne16(val / den);
}

// ---------------------------------------------------------------------------
// Single-pass attention (round-8 validated) — fallback for small ws.
// ---------------------------------------------------------------------------
__global__ __launch_bounds__(128) void k_attn_mono(const ushort* __restrict__ Qs,
                                                   const ushort* __restrict__ Ks,
                                                   const ushort* __restrict__ Vt,
                                                   ushort* __restrict__ O) {
  __shared__ ushort plds[2][32][68];

  const int tid = threadIdx.x;
  const int l = tid & 63;
  const int wid = tid >> 6;
  const int l31 = l & 31, lhi = l >> 5;
  const int bh = blockIdx.y;
  const int q0 = blockIdx.x * 64 + wid * 32;

  FragU aq0, aq1;
  {
    const ushort* qp = Qs + ((size_t)bh * 1024 + q0 + l31) * 32 + lhi * 8;
    aq0.q = *reinterpret_cast<const uint4*>(qp);
    aq1.q = *reinterpret_cast<const uint4*>(qp + 16);
  }

  const ushort* kbase = Ks + (size_t)bh * 1024 * 32;
  const ushort* vbase = Vt + (size_t)bh * 64 * 1024;

  f32x16 oacc0 = 0.0f, oacc1 = 0.0f;
  float pden[16];
#pragma unroll
  for (int r = 0; r < 16; ++r) pden[r] = 0.f;

  for (int kt = 0; kt < 16; ++kt) {
    const int k0 = kt * 64;
    f32x16 sacc[2];
    sacc[0] = 0.0f;
    sacc[1] = 0.0f;
#pragma unroll
    for (int nt = 0; nt < 2; ++nt) {
      const ushort* kp = kbase + (size_t)(k0 + nt * 32 + l31) * 32 + lhi * 8;
      FragU b0, b1;
      b0.q = *reinterpret_cast<const uint4*>(kp);
      b1.q = *reinterpret_cast<const uint4*>(kp + 16);
      sacc[nt] = MFMA(aq0.v, b0.v, sacc[nt]);
      sacc[nt] = MFMA(aq1.v, b1.v, sacc[nt]);
    }
#pragma unroll
    for (int nt = 0; nt < 2; ++nt) {
#pragma unroll
      for (int r = 0; r < 16; ++r) {
        float e = __expf(sacc[nt][r] * SCALE_F);
        pden[r] += e;
        int q = (r & 3) + ((r >> 2) << 3) + 4 * lhi;
        plds[wid][q][nt * 32 + l31] = (ushort)rne16(e);
      }
    }
    __builtin_amdgcn_wave_barrier();
#pragma unroll
    for (int kst = 0; kst < 4; ++kst) {
      FragU ap;
      const ushort* pp = &plds[wid][l31][kst * 16 + lhi * 8];
      uint2 plo = *reinterpret_cast<const uint2*>(pp);
      uint2 phi = *reinterpret_cast<const uint2*>(pp + 4);
      ap.q = make_uint4(plo.x, plo.y, phi.x, phi.y);
      FragU bv0, bv1;
      const ushort* vp0 = vbase + (size_t)l31 * 1024 + k0 + kst * 16 + lhi * 8;
      bv0.q = *reinterpret_cast<const uint4*>(vp0);
      bv1.q = *reinterpret_cast<const uint4*>(vp0 + 32 * 1024);
      oacc0 = MFMA(ap.v, bv0.v, oacc0);
      oacc1 = MFMA(ap.v, bv1.v, oacc1);
    }
  }

#pragma unroll
  for (int r = 0; r < 16; ++r) {
    float s = pden[r];
    s += __shfl_xor(s, 1);
    s += __shfl_xor(s, 2);
    s += __shfl_xor(s, 4);
    s += __shfl_xor(s, 8);
    s += __shfl_xor(s, 16);
    pden[r] = 1.0f / s;
  }

  const int b = bh >> 4, h = bh & 15;
#pragma unroll
  for (int r = 0; r < 16; ++r) {
    int q = q0 + (r & 3) + ((r >> 2) << 3) + 4 * lhi;
    size_t row = ((size_t)b * 1024 + q) * 1024 + h * 64;
    O[row + l31] = (ushort)rne16(oacc0[r] * pden[r]);
    O[row + 32 + l31] = (ushort)rne16(oacc1[r] * pden[r]);
  }
}

// ---------------------------------------------------------------------------
// Final projection (validated round-10): depth-2 pipeline.
// ---------------------------------------------------------------------------
__global__ __launch_bounds__(256) void k_final(const ushort* __restrict__ Xb,
                                               const ushort* __restrict__ Wb,
                                               float* __restrict__ Y) {
  __shared__ __align__(16) char smem[16384];

  const int m0 = blockIdx.y * 64;
  const int n0 = blockIdx.x * 64;
  const int tid = threadIdx.x;
  const int l = tid & 63;
  const int wid = tid >> 6;
  const int wr = wid >> 1, wc = wid & 1;
  const int l31 = l & 31, lhi = l >> 5;
  const int sr = tid >> 2;
  const int sc = tid & 3;

  const int offA = sr * 64 + ((sc ^ ((sr >> 1) & 3)) << 4);
  const int offB = 4096 + offA;
  const ushort* apsrc = Xb + (size_t)(m0 + sr) * 1024 + sc * 8;
  const ushort* bpsrc = Wb + (size_t)(n0 + sr) * 1024 + sc * 8;

  f32x16 acc = 0.0f;

  {
    *reinterpret_cast<uint4*>(smem + offA) =
        *reinterpret_cast<const uint4*>(apsrc);
    *reinterpret_cast<uint4*>(smem + offB) =
        *reinterpret_cast<const uint4*>(bpsrc);
  }
  uint4 ra = *reinterpret_cast<const uint4*>(apsrc + 32);
  uint4 rb = *reinterpret_cast<const uint4*>(bpsrc + 32);
  __syncthreads();

  int cur = 0;
#pragma unroll 4
  for (int t = 0; t < 32; ++t) {
    uint4 na, nb;
    if (t < 30) {
      const int kn = (t + 2) * 32;
      na = *reinterpret_cast<const uint4*>(apsrc + kn);
      nb = *reinterpret_cast<const uint4*>(bpsrc + kn);
    }

    const char* base = smem + cur * 8192;
#pragma unroll
    for (int kst = 0; kst < 2; ++kst) {
      FragU ah, bh;
      int row = wr * 32 + l31;
      int cc = (kst * 2 + lhi) ^ ((row >> 1) & 3);
      ah.q = *reinterpret_cast<const uint4*>(base + row * 64 + cc * 16);
      int brow = wc * 32 + l31;
      int bcc = (kst * 2 + lhi) ^ ((brow >> 1) & 3);
      bh.q = *reinterpret_cast<const uint4*>(base + 4096 + brow * 64 + bcc * 16);
      acc = MFMA(ah.v, bh.v, acc);
    }

    if (t < 31) {
      char* dst = smem + (cur ^ 1) * 8192;
      *reinterpret_cast<uint4*>(dst + offA) = ra;
      *reinterpret_cast<uint4*>(dst + offB) = rb;
      __syncthreads();
      cur ^= 1;
      if (t < 30) { ra = na; rb = nb; }
    }
  }

#pragma unroll
  for (int j = 0; j < 16; ++j) {
    int rl = (j & 3) + ((j >> 2) & 3) * 8 + 4 * lhi;
    int m = m0 + wr * 32 + rl;
    Y[(size_t)m * 1024 + n0 + wc * 32 + l31] = acc[j];
  }
}

// ---------------------------------------------------------------------------
extern "C" void kernel_launch(void* const* d_in, const int* in_sizes, int n_in,
                              void* d_out, int out_size, void* d_ws,
                              size_t ws_size, hipStream_t stream) {
  const float* x = (const float*)d_in[0];
  const float* Wq = (const float*)d_in[1];
  const float* Wk = (const float*)d_in[2];
  const float* Wv = (const float*)d_in[3];
  const float* Wo = (const float*)d_in[4];
  const float* tpl = (const float*)d_in[5];
  const float* proj = (const float*)d_in[6];
  float* out = (float*)d_out;

  char* ws = (char*)d_ws;
  size_t off = 0;
  auto alloc = [&](size_t bytes) {
    void* p = ws + off;
    off += (bytes + 255) & ~(size_t)255;
    return p;
  };

  const size_t MB = 1024 * 1024;
  bool huge = ws_size >= 64 * MB;   // evidence (256MB ws poison): active path
  bool big = ws_size >= 22 * MB;

  ushort *Xb, *Wvb, *obuf;
  float* cs;
  ushort *Ahh, *Ahl, *Wqb, *Wkb, *Wob, *qs, *ks, *vt;
  ushort* Po = nullptr;
  float* Pd = nullptr;

  if (big || huge) {
    Xb = (ushort*)alloc(4 * MB);
    cs = (float*)alloc((size_t)1024 * 64 * 4);
    Ahh = (ushort*)alloc((size_t)16 * 32 * 64 * 2);
    Ahl = (ushort*)alloc((size_t)16 * 32 * 64 * 2);
    Wqb = (ushort*)alloc(2 * MB);
    Wkb = (ushort*)alloc(2 * MB);
    Wvb = (ushort*)alloc(2 * MB);
    Wob = (ushort*)alloc(2 * MB);
    qs = (ushort*)alloc(2 * MB);
    ks = (ushort*)alloc(2 * MB);
    vt = (ushort*)alloc(4 * MB);
    if (huge) {
      Po = (ushort*)alloc(16 * MB);
      Pd = (float*)alloc((size_t)4 * 32768 * 4);
    }
    obuf = Xb;  // Xb dead after k_qkv
  } else {
    cs = (float*)alloc((size_t)1024 * 64 * 4);
    Ahh = (ushort*)alloc((size_t)16 * 32 * 64 * 2);
    Ahl = (ushort*)alloc((size_t)16 * 32 * 64 * 2);
    Wqb = (ushort*)alloc(2 * MB);
    Wkb = (ushort*)alloc(2 * MB);
    Wob = (ushort*)alloc(2 * MB);
    qs = (ushort*)alloc(2 * MB);
    ks = (ushort*)alloc(2 * MB);
    vt = (ushort*)alloc(4 * MB);
    obuf = (ushort*)ws;
    Xb = (ushort*)d_out;
    Wvb = (ushort*)((char*)d_out + 4 * MB);
  }

  k_prep<<<dim3(3328), dim3(256), 0, stream>>>(x, Wq, Wk, Wv, Wo, tpl, proj,
                                               Xb, Wqb, Wkb, Wvb, Wob, cs, Ahh,
                                               Ahl);
  k_qkv<<<dim3(16, 16, 3), dim3(256), 0, stream>>>(Xb, Wqb, Wkb, Wvb, Ahh, Ahl,
                                                   cs, qs, ks, vt);
  if (huge) {
    k_attn<<<dim3(16, 32, 4), dim3(128), 0, stream>>>(qs, ks, vt, Po, Pd);
    k_attnred<<<dim3(8192), dim3(256), 0, stream>>>(Po, Pd, obuf);
  } else {
    k_attn_mono<<<dim3(16, 32), dim3(128), 0, stream>>>(qs, ks, vt, obuf);
  }
  k_final<<<dim3(16, 32), dim3(256), 0, stream>>>(obuf, Wob, out);
}